// Round 1
// baseline (15115.312 us; speedup 1.0000x reference)
//
#include <hip/hip_runtime.h>
#include <hip/hip_bf16.h>

// Problem dims (fixed by reference setup_inputs)
#define BB 2
#define TT 2048
#define DD 512
#define FF 2048
#define HH 8
#define DH 64
#define LL 2
#define MM (BB*TT)   // 4096 rows

// ---------------------------------------------------------------------------
// LayerNorm: one block (256 threads) per row of 512 floats.
// ---------------------------------------------------------------------------
__global__ __launch_bounds__(256) void ln_kernel(const float* __restrict__ x,
                                                 const float* __restrict__ g,
                                                 const float* __restrict__ b,
                                                 float* __restrict__ out)
{
    const int row = blockIdx.x;
    const int tid = threadIdx.x;
    const float2 v = ((const float2*)(x + (size_t)row * DD))[tid];
    float s = v.x + v.y;
    float q = v.x * v.x + v.y * v.y;
    #pragma unroll
    for (int off = 32; off; off >>= 1) {
        s += __shfl_down(s, off);
        q += __shfl_down(q, off);
    }
    __shared__ float ss[4], qq[4];
    const int wid = tid >> 6;
    if ((tid & 63) == 0) { ss[wid] = s; qq[wid] = q; }
    __syncthreads();
    s = ss[0] + ss[1] + ss[2] + ss[3];
    q = qq[0] + qq[1] + qq[2] + qq[3];
    const float mean = s * (1.0f / DD);
    const float var = q * (1.0f / DD) - mean * mean;
    const float inv = rsqrtf(var + 1e-6f);
    const float2 gg = ((const float2*)g)[tid];
    const float2 bb = ((const float2*)b)[tid];
    float2 o;
    o.x = gg.x * (v.x - mean) * inv + bb.x;
    o.y = gg.y * (v.y - mean) * inv + bb.y;
    ((float2*)(out + (size_t)row * DD))[tid] = o;
}

// ---------------------------------------------------------------------------
// fp32 tiled GEMM: C[M,N] = scale * A[M,K] @ W[K,N]  (+ residual) (ReLU opt.)
// 64x64 tile, BK=16, 256 threads, 4x4 per thread.
// ---------------------------------------------------------------------------
template<bool RELU>
__global__ __launch_bounds__(256) void gemm_kernel(const float* __restrict__ A,
                                                   const float* __restrict__ W,
                                                   const float* __restrict__ res,
                                                   float* __restrict__ C,
                                                   int M, int N, int K, float scale)
{
    __shared__ float As[16][65];
    __shared__ float Bs[16][68];
    const int tid = threadIdx.x;
    const int bm = blockIdx.y << 6, bn = blockIdx.x << 6;
    const int ar = tid >> 2, ac = (tid & 3) << 2;   // A stage: 64 rows x 16 k
    const int wr = tid >> 4, wc = (tid & 15) << 2;  // B stage: 16 k x 64 cols
    const int cr = (tid >> 4) << 2, cc = (tid & 15) << 2;
    float acc[4][4] = {};
    const float* Ap = A + (size_t)(bm + ar) * K + ac;
    const float* Wp = W + (size_t)wr * N + (bn + wc);
    for (int k0 = 0; k0 < K; k0 += 16) {
        const float4 a4 = *(const float4*)(Ap + k0);
        const float4 b4 = *(const float4*)(Wp + (size_t)k0 * N);
        __syncthreads();  // protect previous iteration's reads
        As[ac + 0][ar] = a4.x;
        As[ac + 1][ar] = a4.y;
        As[ac + 2][ar] = a4.z;
        As[ac + 3][ar] = a4.w;
        *(float4*)&Bs[wr][wc] = b4;
        __syncthreads();
        #pragma unroll
        for (int kk = 0; kk < 16; ++kk) {
            float av[4], bv[4];
            #pragma unroll
            for (int i = 0; i < 4; ++i) av[i] = As[kk][cr + i];
            #pragma unroll
            for (int j = 0; j < 4; ++j) bv[j] = Bs[kk][cc + j];
            #pragma unroll
            for (int i = 0; i < 4; ++i)
                #pragma unroll
                for (int j = 0; j < 4; ++j) acc[i][j] += av[i] * bv[j];
        }
    }
    #pragma unroll
    for (int i = 0; i < 4; ++i) {
        const int m = bm + cr + i;
        #pragma unroll
        for (int j = 0; j < 4; ++j) {
            const int n = bn + cc + j;
            float vv = acc[i][j] * scale;
            if (RELU) vv = fmaxf(vv, 0.f);
            const size_t idx = (size_t)m * N + n;
            if (res) vv += res[idx];
            C[idx] = vv;
        }
    }
}

// ---------------------------------------------------------------------------
// Flash attention, fp32. One wave (64 threads) per (b, h, 64 q-rows).
// Each lane owns one q row (64 regs) + O accumulator (64 regs).
// K/V tiles (32x64) staged in LDS; inner reads are wave-uniform (broadcast).
// ---------------------------------------------------------------------------
template<bool CAUSAL, bool ACCUM, bool STORE_ML>
__global__ __launch_bounds__(64) void flash_kernel(const float* __restrict__ q,
                                                   const float* __restrict__ k,
                                                   const float* __restrict__ v,
                                                   float* __restrict__ out,
                                                   float* __restrict__ ml)
{
    const int tid = threadIdx.x;
    const int q0 = blockIdx.x << 6;
    const int h = blockIdx.y;
    const int b = blockIdx.z;
    const int row = q0 + tid;

    const float* qp = q + ((size_t)(b * TT + row) * DD) + h * DH;
    float qr[DH];
    #pragma unroll
    for (int d = 0; d < DH; ++d) qr[d] = qp[d];
    float acc[DH];
    #pragma unroll
    for (int d = 0; d < DH; ++d) acc[d] = 0.f;
    float mval = -1e30f, lval = 0.f;

    __shared__ float Ks[32][64];
    __shared__ float Vs[32][64];
    const float* kbase = k + (size_t)b * TT * DD + h * DH;
    const float* vbase = v + (size_t)b * TT * DD + h * DH;

    const int kend = CAUSAL ? (q0 + 64) : TT;
    for (int kt = 0; kt < kend; kt += 32) {
        __syncthreads();
        #pragma unroll
        for (int ii = 0; ii < 8; ++ii) {
            const int i = tid + ii * 64;
            const int r = i >> 4, c4 = (i & 15) << 2;
            *(float4*)&Ks[r][c4] = *(const float4*)(kbase + (size_t)(kt + r) * DD + c4);
            *(float4*)&Vs[r][c4] = *(const float4*)(vbase + (size_t)(kt + r) * DD + c4);
        }
        __syncthreads();
        float sv[32];
        #pragma unroll
        for (int j = 0; j < 32; ++j) {
            float s = 0.f;
            #pragma unroll
            for (int d = 0; d < DH; ++d) s += qr[d] * Ks[j][d];
            if (CAUSAL) s = (kt + j <= row) ? s : -1e30f;
            sv[j] = s;
        }
        float mt = mval;
        #pragma unroll
        for (int j = 0; j < 32; ++j) mt = fmaxf(mt, sv[j]);
        const float sc = __expf(mval - mt);
        lval *= sc;
        #pragma unroll
        for (int d = 0; d < DH; ++d) acc[d] *= sc;
        #pragma unroll
        for (int j = 0; j < 32; ++j) {
            const float p = __expf(sv[j] - mt);
            lval += p;
            #pragma unroll
            for (int d = 0; d < DH; ++d) acc[d] += p * Vs[j][d];
        }
        mval = mt;
    }
    const float inv = 1.f / lval;
    float* op = out + ((size_t)(b * TT + row) * DD) + h * DH;
    #pragma unroll
    for (int d = 0; d < DH; ++d) {
        const float vv = acc[d] * inv;
        op[d] = ACCUM ? (op[d] + vv) : vv;
    }
    if (STORE_ML) {
        const size_t mi = (((size_t)b * HH + h) * TT + row) * 2;
        ml[mi] = mval;
        ml[mi + 1] = lval;
    }
}

// ---------------------------------------------------------------------------
// avg accumulation: avg[b,q,k] += (1/(H*L)) * sum_h softmax_h(q.k_c)
// Recomputes logits with stored (m,l). One wave per (b, 64 q-rows, 64 k-cols).
// ---------------------------------------------------------------------------
__global__ __launch_bounds__(64) void avg_kernel(const float* __restrict__ q,
                                                 const float* __restrict__ kc,
                                                 const float* __restrict__ ml,
                                                 float* __restrict__ avg,
                                                 int first)
{
    const int tid = threadIdx.x;
    const int kt0 = blockIdx.x << 6;
    const int q0 = blockIdx.y << 6;
    const int b = blockIdx.z;
    const int row = q0 + tid;

    float acc[64];
    #pragma unroll
    for (int j = 0; j < 64; ++j) acc[j] = 0.f;

    __shared__ float Ks[64][68];  // +4 pad reduces same-bank write conflicts

    for (int h = 0; h < HH; ++h) {
        __syncthreads();
        #pragma unroll
        for (int c4 = 0; c4 < 16; ++c4)
            *(float4*)&Ks[tid][c4 << 2] =
                *(const float4*)(kc + (size_t)(b * TT + kt0 + tid) * DD + h * DH + (c4 << 2));
        __syncthreads();
        float qr[DH];
        const float* qp = q + (size_t)(b * TT + row) * DD + h * DH;
        #pragma unroll
        for (int d = 0; d < DH; ++d) qr[d] = qp[d];
        const size_t mi = (((size_t)b * HH + h) * TT + row) * 2;
        const float m = ml[mi];
        const float invl = 1.f / ml[mi + 1];
        #pragma unroll
        for (int j = 0; j < 64; ++j) {
            float s = 0.f;
            #pragma unroll
            for (int d = 0; d < DH; ++d) s += qr[d] * Ks[j][d];
            acc[j] += __expf(s - m) * invl;
        }
    }
    float* dst = avg + ((size_t)b * TT + row) * TT + kt0;
    #pragma unroll
    for (int j = 0; j < 64; ++j) {
        const float vv = acc[j] * (1.f / (HH * LL));
        dst[j] = first ? vv : (dst[j] + vv);
    }
}

// ---------------------------------------------------------------------------
extern "C" void kernel_launch(void* const* d_in, const int* in_sizes, int n_in,
                              void* d_out, int out_size, void* d_ws, size_t ws_size,
                              hipStream_t stream)
{
    const float* x_in   = (const float*)d_in[0];
    const float* enc_a  = (const float*)d_in[1];
    const float* enc_c  = (const float*)d_in[2];
    const float* sa_wq0 = (const float*)d_in[3];
    const float* sa_wk0 = (const float*)d_in[4];
    const float* sa_wv0 = (const float*)d_in[5];
    const float* sa_wo0 = (const float*)d_in[6];
    const float* ed_wq0 = (const float*)d_in[7];
    const float* ed_wk0 = (const float*)d_in[8];
    const float* ed_wv0 = (const float*)d_in[9];
    const float* ed_wo0 = (const float*)d_in[10];
    const float* ffn_w10 = (const float*)d_in[11];
    const float* ffn_w20 = (const float*)d_in[12];
    const float* ln1_g0 = (const float*)d_in[13];
    const float* ln1_b0 = (const float*)d_in[14];
    const float* ln2_g0 = (const float*)d_in[15];
    const float* ln2_b0 = (const float*)d_in[16];
    const float* ln3_g0 = (const float*)d_in[17];
    const float* ln3_b0 = (const float*)d_in[18];
    const float* out_g  = (const float*)d_in[19];
    const float* out_b  = (const float*)d_in[20];

    const size_t NTD = (size_t)MM * DD;  // 2,097,152 floats
    float* ws = (float*)d_ws;
    float* x_buf  = ws;
    float* h_buf  = x_buf + NTD;
    float* q_buf  = h_buf + NTD;
    float* k1_buf = q_buf + NTD;
    float* v1_buf = k1_buf + NTD;
    float* k2_buf = v1_buf + NTD;
    float* v2_buf = k2_buf + NTD;
    float* attn   = v2_buf + NTD;
    float* ml_buf = attn + NTD;          // 65,536 floats
    float* ffn_buf = q_buf;              // alias: q not live during FFN

    float* x_out   = (float*)d_out;
    float* avg_out = (float*)d_out + NTD;

    hipMemcpyAsync(x_buf, x_in, NTD * sizeof(float), hipMemcpyDeviceToDevice, stream);

    const dim3 gemmDD(DD / 64, MM / 64);   // (8, 64)
    const dim3 gemmDF(FF / 64, MM / 64);   // (32, 64)
    const dim3 flashG(TT / 64, HH, BB);    // (32, 8, 2)
    const dim3 avgG(TT / 64, TT / 64, BB); // (32, 32, 2)
    const float qscale = 0.125f;           // dh^-0.5, dh=64

    for (int i = 0; i < LL; ++i) {
        const size_t wOff = (size_t)i * DD * DD;
        const size_t fOff = (size_t)i * DD * FF;
        const size_t lOff = (size_t)i * DD;

        // --- self attention ---
        ln_kernel<<<MM, 256, 0, stream>>>(x_buf, ln1_g0 + lOff, ln1_b0 + lOff, h_buf);
        gemm_kernel<false><<<gemmDD, 256, 0, stream>>>(h_buf, sa_wq0 + wOff, nullptr, q_buf, MM, DD, DD, qscale);
        gemm_kernel<false><<<gemmDD, 256, 0, stream>>>(h_buf, sa_wk0 + wOff, nullptr, k1_buf, MM, DD, DD, 1.f);
        gemm_kernel<false><<<gemmDD, 256, 0, stream>>>(h_buf, sa_wv0 + wOff, nullptr, v1_buf, MM, DD, DD, 1.f);
        flash_kernel<true, false, false><<<flashG, 64, 0, stream>>>(q_buf, k1_buf, v1_buf, attn, nullptr);
        gemm_kernel<false><<<gemmDD, 256, 0, stream>>>(attn, sa_wo0 + wOff, x_buf, x_buf, MM, DD, DD, 1.f);

        // --- cross attention (enc_a + enc_c, shared weights) ---
        ln_kernel<<<MM, 256, 0, stream>>>(x_buf, ln2_g0 + lOff, ln2_b0 + lOff, h_buf);
        gemm_kernel<false><<<gemmDD, 256, 0, stream>>>(h_buf, ed_wq0 + wOff, nullptr, q_buf, MM, DD, DD, qscale);
        gemm_kernel<false><<<gemmDD, 256, 0, stream>>>(enc_a, ed_wk0 + wOff, nullptr, k1_buf, MM, DD, DD, 1.f);
        gemm_kernel<false><<<gemmDD, 256, 0, stream>>>(enc_a, ed_wv0 + wOff, nullptr, v1_buf, MM, DD, DD, 1.f);
        gemm_kernel<false><<<gemmDD, 256, 0, stream>>>(enc_c, ed_wk0 + wOff, nullptr, k2_buf, MM, DD, DD, 1.f);
        gemm_kernel<false><<<gemmDD, 256, 0, stream>>>(enc_c, ed_wv0 + wOff, nullptr, v2_buf, MM, DD, DD, 1.f);
        flash_kernel<false, false, false><<<flashG, 64, 0, stream>>>(q_buf, k1_buf, v1_buf, attn, nullptr);
        flash_kernel<false, true, true><<<flashG, 64, 0, stream>>>(q_buf, k2_buf, v2_buf, attn, ml_buf);
        avg_kernel<<<avgG, 64, 0, stream>>>(q_buf, k2_buf, ml_buf, avg_out, (i == 0) ? 1 : 0);
        gemm_kernel<false><<<gemmDD, 256, 0, stream>>>(attn, ed_wo0 + wOff, x_buf, x_buf, MM, DD, DD, 1.f);

        // --- FFN ---
        ln_kernel<<<MM, 256, 0, stream>>>(x_buf, ln3_g0 + lOff, ln3_b0 + lOff, h_buf);
        gemm_kernel<true><<<gemmDF, 256, 0, stream>>>(h_buf, ffn_w10 + fOff, nullptr, ffn_buf, MM, FF, DD, 1.f);
        gemm_kernel<false><<<gemmDD, 256, 0, stream>>>(ffn_buf, ffn_w20 + fOff, x_buf, x_buf, MM, DD, FF, 1.f);
    }

    ln_kernel<<<MM, 256, 0, stream>>>(x_buf, out_g, out_b, x_out);
}

// Round 2
// 8031.557 us; speedup vs baseline: 1.8820x; 1.8820x over previous
//
#include <hip/hip_runtime.h>
#include <hip/hip_bf16.h>

// Problem dims (fixed by reference setup_inputs)
#define BB 2
#define TT 2048
#define DD 512
#define FF 2048
#define HH 8
#define DH 64
#define LL 2
#define MM (BB*TT)   // 4096 rows

// ---------------------------------------------------------------------------
// LayerNorm: one block (256 threads) per row of 512 floats.
// ---------------------------------------------------------------------------
__global__ __launch_bounds__(256) void ln_kernel(const float* __restrict__ x,
                                                 const float* __restrict__ g,
                                                 const float* __restrict__ b,
                                                 float* __restrict__ out)
{
    const int row = blockIdx.x;
    const int tid = threadIdx.x;
    const float2 v = ((const float2*)(x + (size_t)row * DD))[tid];
    float s = v.x + v.y;
    float q = v.x * v.x + v.y * v.y;
    #pragma unroll
    for (int off = 32; off; off >>= 1) {
        s += __shfl_down(s, off);
        q += __shfl_down(q, off);
    }
    __shared__ float ss[4], qq[4];
    const int wid = tid >> 6;
    if ((tid & 63) == 0) { ss[wid] = s; qq[wid] = q; }
    __syncthreads();
    s = ss[0] + ss[1] + ss[2] + ss[3];
    q = qq[0] + qq[1] + qq[2] + qq[3];
    const float mean = s * (1.0f / DD);
    const float var = q * (1.0f / DD) - mean * mean;
    const float inv = rsqrtf(var + 1e-6f);
    const float2 gg = ((const float2*)g)[tid];
    const float2 bb = ((const float2*)b)[tid];
    float2 o;
    o.x = gg.x * (v.x - mean) * inv + bb.x;
    o.y = gg.y * (v.y - mean) * inv + bb.y;
    ((float2*)(out + (size_t)row * DD))[tid] = o;
}

// ---------------------------------------------------------------------------
// fp32 tiled GEMM: C[M,N] = scale * (A [+ A2])[M,K] @ W[K,N] (+res) (ReLU opt)
// 64x64 tile, BK=16, 256 threads, 4x4 per thread.
// ---------------------------------------------------------------------------
template<bool RELU, bool SUM2>
__global__ __launch_bounds__(256) void gemm_kernel(const float* __restrict__ A,
                                                   const float* __restrict__ A2,
                                                   const float* __restrict__ W,
                                                   const float* __restrict__ res,
                                                   float* __restrict__ C,
                                                   int M, int N, int K, float scale)
{
    __shared__ float As[16][65];
    __shared__ float Bs[16][68];
    const int tid = threadIdx.x;
    const int bm = blockIdx.y << 6, bn = blockIdx.x << 6;
    const int ar = tid >> 2, ac = (tid & 3) << 2;   // A stage: 64 rows x 16 k
    const int wr = tid >> 4, wc = (tid & 15) << 2;  // B stage: 16 k x 64 cols
    const int cr = (tid >> 4) << 2, cc = (tid & 15) << 2;
    float acc[4][4] = {};
    const float* Ap = A + (size_t)(bm + ar) * K + ac;
    const float* A2p = SUM2 ? (A2 + (size_t)(bm + ar) * K + ac) : nullptr;
    const float* Wp = W + (size_t)wr * N + (bn + wc);
    for (int k0 = 0; k0 < K; k0 += 16) {
        float4 a4 = *(const float4*)(Ap + k0);
        if (SUM2) {
            const float4 a4b = *(const float4*)(A2p + k0);
            a4.x += a4b.x; a4.y += a4b.y; a4.z += a4b.z; a4.w += a4b.w;
        }
        const float4 b4 = *(const float4*)(Wp + (size_t)k0 * N);
        __syncthreads();  // protect previous iteration's reads
        As[ac + 0][ar] = a4.x;
        As[ac + 1][ar] = a4.y;
        As[ac + 2][ar] = a4.z;
        As[ac + 3][ar] = a4.w;
        *(float4*)&Bs[wr][wc] = b4;
        __syncthreads();
        #pragma unroll
        for (int kk = 0; kk < 16; ++kk) {
            float av[4], bv[4];
            #pragma unroll
            for (int i = 0; i < 4; ++i) av[i] = As[kk][cr + i];
            #pragma unroll
            for (int j = 0; j < 4; ++j) bv[j] = Bs[kk][cc + j];
            #pragma unroll
            for (int i = 0; i < 4; ++i)
                #pragma unroll
                for (int j = 0; j < 4; ++j) acc[i][j] += av[i] * bv[j];
        }
    }
    #pragma unroll
    for (int i = 0; i < 4; ++i) {
        const int m = bm + cr + i;
        #pragma unroll
        for (int j = 0; j < 4; ++j) {
            const int n = bn + cc + j;
            float vv = acc[i][j] * scale;
            if (RELU) vv = fmaxf(vv, 0.f);
            const size_t idx = (size_t)m * N + n;
            if (res) vv += res[idx];
            C[idx] = vv;
        }
    }
}

// ---------------------------------------------------------------------------
// Flash attention, fp32, KV-split over 4 waves per block.
// Block = 256 threads = 4 waves; all waves share the same 64 q-rows
// (1 row per lane) but process a strided subset of KV tiles (32 rows each),
// each staging K/V into its own LDS quadrant (wave-synchronous, no barrier).
// Partials (m,l,acc) merged in LDS at the end.
// DUAL: blockIdx.z = b*2+which selects (ka,va,outa) / (kc,vc,outc).
// ---------------------------------------------------------------------------
template<bool CAUSAL, bool DUAL, bool STOREML>
__global__ __launch_bounds__(256, 1) void flash4_kernel(
    const float* __restrict__ q,
    const float* __restrict__ ka, const float* __restrict__ va,
    const float* __restrict__ kc, const float* __restrict__ vc,
    float* __restrict__ outa, float* __restrict__ outc,
    float* __restrict__ ml)
{
    __shared__ __align__(16) float smem[4 * 64 * 69];  // 70656 B
    const int tid = threadIdx.x;
    const int lane = tid & 63;
    const int w = tid >> 6;
    const int q0 = blockIdx.x << 6;
    const int h = blockIdx.y;
    int b = blockIdx.z;
    int which = 0;
    if (DUAL) { which = b & 1; b >>= 1; }
    const float* k = (DUAL && which) ? kc : ka;
    const float* v = (DUAL && which) ? vc : va;
    float* out = (DUAL && which) ? outc : outa;

    const int row = q0 + lane;
    const float* qp = q + ((size_t)(b * TT + row) * DD) + h * DH;
    float qr[DH];
    #pragma unroll
    for (int d = 0; d < DH; ++d) qr[d] = qp[d];
    float acc[DH];
    #pragma unroll
    for (int d = 0; d < DH; ++d) acc[d] = 0.f;
    float mval = -1e30f, lval = 0.f;

    float* Ks = smem + w * 4096;   // 32x64 K tile for this wave
    float* Vs = Ks + 2048;         // 32x64 V tile
    const float* kbase = k + (size_t)b * TT * DD + h * DH;
    const float* vbase = v + (size_t)b * TT * DD + h * DH;

    const int nt = (CAUSAL ? (q0 + 64) : TT) >> 5;   // KV tiles of 32
    for (int t = w; t < nt; t += 4) {
        const int kt = t << 5;
        #pragma unroll
        for (int ii = 0; ii < 8; ++ii) {
            const int i = lane + ii * 64;
            const int r = i >> 4, c4 = (i & 15) << 2;
            *(float4*)(Ks + r * 64 + c4) = *(const float4*)(kbase + (size_t)(kt + r) * DD + c4);
            *(float4*)(Vs + r * 64 + c4) = *(const float4*)(vbase + (size_t)(kt + r) * DD + c4);
        }
        __builtin_amdgcn_sched_barrier(0);  // keep wave-sync write->read order
        float sv[32];
        #pragma unroll
        for (int j = 0; j < 32; ++j) {
            float s = 0.f;
            #pragma unroll
            for (int d = 0; d < DH; ++d) s += qr[d] * Ks[j * 64 + d];
            if (CAUSAL) s = (kt + j <= row) ? s : -1e30f;
            sv[j] = s;
        }
        float mt = mval;
        #pragma unroll
        for (int j = 0; j < 32; ++j) mt = fmaxf(mt, sv[j]);
        const float sc = __expf(mval - mt);
        lval *= sc;
        #pragma unroll
        for (int d = 0; d < DH; ++d) acc[d] *= sc;
        #pragma unroll
        for (int j = 0; j < 32; ++j) {
            const float p = __expf(sv[j] - mt);
            lval += p;
            #pragma unroll
            for (int d = 0; d < DH; ++d) acc[d] += p * Vs[j * 64 + d];
        }
        mval = mt;
        __builtin_amdgcn_sched_barrier(0);
    }

    __syncthreads();  // all waves done reading staging region
    float* Crow = smem + (size_t)(w * 64 + lane) * 69;
    #pragma unroll
    for (int d = 0; d < DH; ++d) Crow[d] = acc[d];
    Crow[64] = mval;
    Crow[65] = lval;
    __syncthreads();

    // combine: thread t -> row r = t>>2, d-quarter dq = t&3 (16 d's each)
    {
        const int r = tid >> 2, dq = tid & 3;
        float mw[4], lw[4];
        #pragma unroll
        for (int u = 0; u < 4; ++u) {
            mw[u] = smem[(size_t)(u * 64 + r) * 69 + 64];
            lw[u] = smem[(size_t)(u * 64 + r) * 69 + 65];
        }
        const float M = fmaxf(fmaxf(mw[0], mw[1]), fmaxf(mw[2], mw[3]));
        float sc[4], L = 0.f;
        #pragma unroll
        for (int u = 0; u < 4; ++u) { sc[u] = __expf(mw[u] - M); L += sc[u] * lw[u]; }
        const float invL = 1.f / L;
        float* op = out + ((size_t)(b * TT + q0 + r) * DD) + h * DH + dq * 16;
        #pragma unroll
        for (int d = 0; d < 16; ++d) {
            float o = 0.f;
            #pragma unroll
            for (int u = 0; u < 4; ++u) o += sc[u] * smem[(size_t)(u * 64 + r) * 69 + dq * 16 + d];
            op[d] = o * invL;
        }
        if (STOREML && (!DUAL || which == 1) && dq == 0) {
            const size_t mi = (((size_t)b * HH + h) * TT + q0 + r) * 2;
            ml[mi] = M;
            ml[mi + 1] = L;
        }
    }
}

// ---------------------------------------------------------------------------
// avg accumulation: avg[b,q,k] += (1/(H*L)) * sum_h softmax_h(q.k_c)
// Recomputes logits with stored (m,l). One wave per (b, 64 q-rows, 64 k-cols).
// ---------------------------------------------------------------------------
__global__ __launch_bounds__(64) void avg_kernel(const float* __restrict__ q,
                                                 const float* __restrict__ kc,
                                                 const float* __restrict__ ml,
                                                 float* __restrict__ avg,
                                                 int first)
{
    const int tid = threadIdx.x;
    const int kt0 = blockIdx.x << 6;
    const int q0 = blockIdx.y << 6;
    const int b = blockIdx.z;
    const int row = q0 + tid;

    float acc[64];
    #pragma unroll
    for (int j = 0; j < 64; ++j) acc[j] = 0.f;

    __shared__ float Ks[64][68];

    for (int h = 0; h < HH; ++h) {
        __syncthreads();
        #pragma unroll
        for (int c4 = 0; c4 < 16; ++c4)
            *(float4*)&Ks[tid][c4 << 2] =
                *(const float4*)(kc + (size_t)(b * TT + kt0 + tid) * DD + h * DH + (c4 << 2));
        __syncthreads();
        float qr[DH];
        const float* qp = q + (size_t)(b * TT + row) * DD + h * DH;
        #pragma unroll
        for (int d = 0; d < DH; ++d) qr[d] = qp[d];
        const size_t mi = (((size_t)b * HH + h) * TT + row) * 2;
        const float m = ml[mi];
        const float invl = 1.f / ml[mi + 1];
        #pragma unroll
        for (int j = 0; j < 64; ++j) {
            float s = 0.f;
            #pragma unroll
            for (int d = 0; d < DH; ++d) s += qr[d] * Ks[j][d];
            acc[j] += __expf(s - m) * invl;
        }
    }
    float* dst = avg + ((size_t)b * TT + row) * TT + kt0;
    #pragma unroll
    for (int j = 0; j < 64; ++j) {
        const float vv = acc[j] * (1.f / (HH * LL));
        dst[j] = first ? vv : (dst[j] + vv);
    }
}

// ---------------------------------------------------------------------------
extern "C" void kernel_launch(void* const* d_in, const int* in_sizes, int n_in,
                              void* d_out, int out_size, void* d_ws, size_t ws_size,
                              hipStream_t stream)
{
    const float* x_in   = (const float*)d_in[0];
    const float* enc_a  = (const float*)d_in[1];
    const float* enc_c  = (const float*)d_in[2];
    const float* sa_wq0 = (const float*)d_in[3];
    const float* sa_wk0 = (const float*)d_in[4];
    const float* sa_wv0 = (const float*)d_in[5];
    const float* sa_wo0 = (const float*)d_in[6];
    const float* ed_wq0 = (const float*)d_in[7];
    const float* ed_wk0 = (const float*)d_in[8];
    const float* ed_wv0 = (const float*)d_in[9];
    const float* ed_wo0 = (const float*)d_in[10];
    const float* ffn_w10 = (const float*)d_in[11];
    const float* ffn_w20 = (const float*)d_in[12];
    const float* ln1_g0 = (const float*)d_in[13];
    const float* ln1_b0 = (const float*)d_in[14];
    const float* ln2_g0 = (const float*)d_in[15];
    const float* ln2_b0 = (const float*)d_in[16];
    const float* ln3_g0 = (const float*)d_in[17];
    const float* ln3_b0 = (const float*)d_in[18];
    const float* out_g  = (const float*)d_in[19];
    const float* out_b  = (const float*)d_in[20];

    const size_t NTD = (size_t)MM * DD;  // 2,097,152 floats
    float* ws = (float*)d_ws;
    float* x_buf  = ws;
    float* h_buf  = x_buf + NTD;
    float* q_buf  = h_buf + NTD;
    float* k1_buf = q_buf + NTD;
    float* v1_buf = k1_buf + NTD;
    float* k2_buf = v1_buf + NTD;
    float* v2_buf = k2_buf + NTD;
    float* attn   = v2_buf + NTD;
    float* ml_buf = attn + NTD;          // 65,536 floats
    float* ffn_buf = q_buf;              // alias: q not live during FFN
    float* attn_c  = h_buf;              // alias: h not live after q/k/v proj

    float* x_out   = (float*)d_out;
    float* avg_out = (float*)d_out + NTD;

    hipMemcpyAsync(x_buf, x_in, NTD * sizeof(float), hipMemcpyDeviceToDevice, stream);

    const dim3 gemmDD(DD / 64, MM / 64);   // (8, 64)
    const dim3 gemmDF(FF / 64, MM / 64);   // (32, 64)
    const dim3 flashSelfG(TT / 64, HH, BB);      // (32, 8, 2)
    const dim3 flashCrossG(TT / 64, HH, BB * 2); // (32, 8, 4) dual-fused
    const dim3 avgG(TT / 64, TT / 64, BB); // (32, 32, 2)
    const float qscale = 0.125f;           // dh^-0.5, dh=64

    for (int i = 0; i < LL; ++i) {
        const size_t wOff = (size_t)i * DD * DD;
        const size_t fOff = (size_t)i * DD * FF;
        const size_t lOff = (size_t)i * DD;

        // --- self attention ---
        ln_kernel<<<MM, 256, 0, stream>>>(x_buf, ln1_g0 + lOff, ln1_b0 + lOff, h_buf);
        gemm_kernel<false,false><<<gemmDD, 256, 0, stream>>>(h_buf, nullptr, sa_wq0 + wOff, nullptr, q_buf, MM, DD, DD, qscale);
        gemm_kernel<false,false><<<gemmDD, 256, 0, stream>>>(h_buf, nullptr, sa_wk0 + wOff, nullptr, k1_buf, MM, DD, DD, 1.f);
        gemm_kernel<false,false><<<gemmDD, 256, 0, stream>>>(h_buf, nullptr, sa_wv0 + wOff, nullptr, v1_buf, MM, DD, DD, 1.f);
        flash4_kernel<true, false, false><<<flashSelfG, 256, 0, stream>>>(
            q_buf, k1_buf, v1_buf, nullptr, nullptr, attn, nullptr, nullptr);
        gemm_kernel<false,false><<<gemmDD, 256, 0, stream>>>(attn, nullptr, sa_wo0 + wOff, x_buf, x_buf, MM, DD, DD, 1.f);

        // --- cross attention (enc_a + enc_c, shared weights, fused dispatch) ---
        ln_kernel<<<MM, 256, 0, stream>>>(x_buf, ln2_g0 + lOff, ln2_b0 + lOff, h_buf);
        gemm_kernel<false,false><<<gemmDD, 256, 0, stream>>>(h_buf, nullptr, ed_wq0 + wOff, nullptr, q_buf, MM, DD, DD, qscale);
        gemm_kernel<false,false><<<gemmDD, 256, 0, stream>>>(enc_a, nullptr, ed_wk0 + wOff, nullptr, k1_buf, MM, DD, DD, 1.f);
        gemm_kernel<false,false><<<gemmDD, 256, 0, stream>>>(enc_a, nullptr, ed_wv0 + wOff, nullptr, v1_buf, MM, DD, DD, 1.f);
        gemm_kernel<false,false><<<gemmDD, 256, 0, stream>>>(enc_c, nullptr, ed_wk0 + wOff, nullptr, k2_buf, MM, DD, DD, 1.f);
        gemm_kernel<false,false><<<gemmDD, 256, 0, stream>>>(enc_c, nullptr, ed_wv0 + wOff, nullptr, v2_buf, MM, DD, DD, 1.f);
        // note: attn_c aliases h_buf (h no longer needed; flash reads only q/k/v)
        flash4_kernel<false, true, true><<<flashCrossG, 256, 0, stream>>>(
            q_buf, k1_buf, v1_buf, k2_buf, v2_buf, attn, attn_c, ml_buf);
        avg_kernel<<<avgG, 64, 0, stream>>>(q_buf, k2_buf, ml_buf, avg_out, (i == 0) ? 1 : 0);
        gemm_kernel<false,true><<<gemmDD, 256, 0, stream>>>(attn, attn_c, ed_wo0 + wOff, x_buf, x_buf, MM, DD, DD, 1.f);

        // --- FFN ---
        ln_kernel<<<MM, 256, 0, stream>>>(x_buf, ln3_g0 + lOff, ln3_b0 + lOff, h_buf);
        gemm_kernel<true,false><<<gemmDF, 256, 0, stream>>>(h_buf, nullptr, ffn_w10 + fOff, nullptr, ffn_buf, MM, FF, DD, 1.f);
        gemm_kernel<false,false><<<gemmDD, 256, 0, stream>>>(ffn_buf, nullptr, ffn_w20 + fOff, x_buf, x_buf, MM, DD, FF, 1.f);
    }

    ln_kernel<<<MM, 256, 0, stream>>>(x_buf, out_g, out_b, x_out);
}

// Round 3
// 3777.043 us; speedup vs baseline: 4.0019x; 2.1264x over previous
//
#include <hip/hip_runtime.h>
#include <hip/hip_bf16.h>

// Problem dims (fixed by reference setup_inputs)
#define BB 2
#define TT 2048
#define DD 512
#define FF 2048
#define HH 8
#define DH 64
#define LL 2
#define MM (BB*TT)   // 4096 rows

typedef __attribute__((ext_vector_type(8))) short bf16x8;
typedef __attribute__((ext_vector_type(4))) float f32x4;

__device__ __forceinline__ float bf2f(unsigned short u) {
    return __uint_as_float(((unsigned int)u) << 16);
}
__device__ __forceinline__ unsigned short f2bf(float f) {
    unsigned int u = __float_as_uint(f);
    u += 0x7fffu + ((u >> 16) & 1u);   // round-to-nearest-even
    return (unsigned short)(u >> 16);
}
__device__ __forceinline__ void gload16(const void* g, void* l) {
    __builtin_amdgcn_global_load_lds((__attribute__((address_space(1))) void*)g,
                                     (__attribute__((address_space(3))) void*)l, 16, 0, 0);
}

// ---------------------------------------------------------------------------
// LayerNorm: one block (256 threads) per row of 512 floats. bf16 or f32 out.
// ---------------------------------------------------------------------------
template<bool BF16OUT>
__global__ __launch_bounds__(256) void ln_kernel(const float* __restrict__ x,
                                                 const float* __restrict__ g,
                                                 const float* __restrict__ b,
                                                 void* __restrict__ out)
{
    const int row = blockIdx.x;
    const int tid = threadIdx.x;
    const float2 v = ((const float2*)(x + (size_t)row * DD))[tid];
    float s = v.x + v.y;
    float q = v.x * v.x + v.y * v.y;
    #pragma unroll
    for (int off = 32; off; off >>= 1) {
        s += __shfl_down(s, off);
        q += __shfl_down(q, off);
    }
    __shared__ float ss[4], qq[4];
    const int wid = tid >> 6;
    if ((tid & 63) == 0) { ss[wid] = s; qq[wid] = q; }
    __syncthreads();
    s = ss[0] + ss[1] + ss[2] + ss[3];
    q = qq[0] + qq[1] + qq[2] + qq[3];
    const float mean = s * (1.0f / DD);
    const float var = q * (1.0f / DD) - mean * mean;
    const float inv = rsqrtf(var + 1e-6f);
    const float2 gg = ((const float2*)g)[tid];
    const float2 bb = ((const float2*)b)[tid];
    const float ox = gg.x * (v.x - mean) * inv + bb.x;
    const float oy = gg.y * (v.y - mean) * inv + bb.y;
    if (BF16OUT) {
        const unsigned int pk = (unsigned int)f2bf(ox) | ((unsigned int)f2bf(oy) << 16);
        ((unsigned int*)((unsigned short*)out + (size_t)row * DD))[tid] = pk;
    } else {
        float2 o; o.x = ox; o.y = oy;
        ((float2*)((float*)out + (size_t)row * DD))[tid] = o;
    }
}

// ---------------------------------------------------------------------------
// fp32 -> bf16 elementwise (enc inputs). n multiple of 2048.
// ---------------------------------------------------------------------------
__global__ __launch_bounds__(256) void cvt_kernel(const float* __restrict__ src,
                                                  unsigned short* __restrict__ dst, int n)
{
    const int i = (blockIdx.x * 256 + threadIdx.x) * 8;
    if (i >= n) return;
    const float4 a = *(const float4*)(src + i);
    const float4 b = *(const float4*)(src + i + 4);
    unsigned short o[8];
    o[0] = f2bf(a.x); o[1] = f2bf(a.y); o[2] = f2bf(a.z); o[3] = f2bf(a.w);
    o[4] = f2bf(b.x); o[5] = f2bf(b.y); o[6] = f2bf(b.z); o[7] = f2bf(b.w);
    *(bf16x8*)(dst + i) = *(bf16x8*)o;
}

// ---------------------------------------------------------------------------
// Weight convert + transpose: src fp32 [K][N] -> dst bf16 [N][K]. 32x32 tiles.
// ---------------------------------------------------------------------------
struct CvtJob { const float* s; unsigned short* d; };
struct CvtJobs16 { CvtJob j[16]; };

__global__ __launch_bounds__(256) void cvtT_kernel(CvtJobs16 P, int K, int N)
{
    __shared__ float t[32][33];
    const CvtJob jb = P.j[blockIdx.z];
    const int tx = threadIdx.x & 31, ty = threadIdx.x >> 5;
    const int gk = blockIdx.y << 5, gn = blockIdx.x << 5;
    #pragma unroll
    for (int i = 0; i < 4; ++i)
        t[ty + i * 8][tx] = jb.s[(size_t)(gk + ty + i * 8) * N + gn + tx];
    __syncthreads();
    #pragma unroll
    for (int i = 0; i < 4; ++i)
        jb.d[(size_t)(gn + ty + i * 8) * K + gk + tx] = f2bf(t[tx][ty + i * 8]);
}

// ---------------------------------------------------------------------------
// bf16 MFMA GEMM: C[M,N] = scale * A[M,K] @ Wt[N,K]^T (+res fp32) (ReLU opt).
// 128x128 tile, BK=64, 256 threads = 4 waves (2x2 of 64x64).
// LDS XOR-swizzled (st-16 within 8-row stripes) with pre-swizzled
// global_load_lds sources (rule 21: both-sides-or-neither).
// ---------------------------------------------------------------------------
struct GemmJob {
    const unsigned short* A;
    const unsigned short* Wt;
    const float* res;
    float* Cf;
    unsigned short* Cb;
    float scale;
    int relu;
};
struct GemmJobs6 { GemmJob j[6]; };

__global__ __launch_bounds__(256, 2) void gemm_mfma(GemmJobs6 P, int M, int N, int K)
{
    __shared__ __align__(16) unsigned char lds[32768];   // A: 0..16K, B: 16K..32K
    const GemmJob jb = P.j[blockIdx.z];
    const int tid = threadIdx.x, lane = tid & 63, w = tid >> 6;
    const int bn = blockIdx.x << 7, bm = blockIdx.y << 7;
    const int wr = (w >> 1) << 6, wc = (w & 1) << 6;
    const size_t strA = (size_t)K * 2;   // bytes per row (A and Wt share K)

    f32x4 acc[4][4] = {};
    const int akey = (lane & 7) << 4;        // XOR key for frag reads
    const int frow = lane & 15;
    const int kq = (lane >> 4) << 4;         // 16B sub-slice per lane quarter

    for (int kt = 0; kt < K; kt += 64) {
        __syncthreads();
        #pragma unroll
        for (int c = 0; c < 4; ++c) {
            const int q = c * 4 + w;                 // 1KB chunk id (0..15)
            const int o = (q << 10) + (lane << 4);   // lds byte offset this lane covers
            const int row = o >> 7;                  // tile row (0..127)
            const int colb = (o & 127) ^ ((row & 7) << 4);  // pre-swizzled source col
            gload16((const char*)jb.A + (size_t)(bm + row) * strA + kt * 2 + colb,
                    lds + (q << 10));
            gload16((const char*)jb.Wt + (size_t)(bn + row) * strA + kt * 2 + colb,
                    lds + 16384 + (q << 10));
        }
        asm volatile("s_waitcnt vmcnt(0)" ::: "memory");
        __syncthreads();
        #pragma unroll
        for (int kk = 0; kk < 2; ++kk) {
            bf16x8 av[4], bv[4];
            #pragma unroll
            for (int i = 0; i < 4; ++i) {
                const int rA = wr + (i << 4) + frow;
                av[i] = *(const bf16x8*)(lds + (rA << 7) + ((((kk << 6) + kq)) ^ akey));
                const int rB = wc + (i << 4) + frow;
                bv[i] = *(const bf16x8*)(lds + 16384 + (rB << 7) + ((((kk << 6) + kq)) ^ akey));
            }
            #pragma unroll
            for (int i = 0; i < 4; ++i)
                #pragma unroll
                for (int j = 0; j < 4; ++j)
                    acc[i][j] = __builtin_amdgcn_mfma_f32_16x16x32_bf16(av[i], bv[j], acc[i][j], 0, 0, 0);
        }
    }

    const int crow0 = (lane >> 4) << 2;
    const int ccol = lane & 15;
    #pragma unroll
    for (int i = 0; i < 4; ++i) {
        #pragma unroll
        for (int j = 0; j < 4; ++j) {
            #pragma unroll
            for (int r = 0; r < 4; ++r) {
                const int gm = bm + wr + (i << 4) + crow0 + r;
                const int gn = bn + wc + (j << 4) + ccol;
                float v = acc[i][j][r] * jb.scale;
                if (jb.relu) v = fmaxf(v, 0.f);
                const size_t idx = (size_t)gm * N + gn;
                if (jb.res) v += jb.res[idx];
                if (jb.Cf) jb.Cf[idx] = v;
                if (jb.Cb) jb.Cb[idx] = f2bf(v);
            }
        }
    }
}

// ---------------------------------------------------------------------------
// Flash attention: bf16 q/k/v in, bf16 out, fp32 core. 4-wave KV-split.
// ---------------------------------------------------------------------------
template<bool CAUSAL, bool DUAL, bool STOREML>
__global__ __launch_bounds__(256, 1) void flash4_kernel(
    const unsigned short* __restrict__ q,
    const unsigned short* __restrict__ ka, const unsigned short* __restrict__ va,
    const unsigned short* __restrict__ kc, const unsigned short* __restrict__ vc,
    unsigned short* __restrict__ outa, unsigned short* __restrict__ outc,
    float* __restrict__ ml)
{
    __shared__ __align__(16) float smem[4 * 64 * 69];  // 70656 B
    const int tid = threadIdx.x;
    const int lane = tid & 63;
    const int w = tid >> 6;
    const int q0 = blockIdx.x << 6;
    const int h = blockIdx.y;
    int b = blockIdx.z;
    int which = 0;
    if (DUAL) { which = b & 1; b >>= 1; }
    const unsigned short* k = (DUAL && which) ? kc : ka;
    const unsigned short* v = (DUAL && which) ? vc : va;
    unsigned short* out = (DUAL && which) ? outc : outa;

    const int row = q0 + lane;
    const unsigned short* qp = q + ((size_t)(b * TT + row) * DD) + h * DH;
    float qr[DH];
    #pragma unroll
    for (int c = 0; c < 8; ++c) {
        const bf16x8 q8 = *(const bf16x8*)(qp + c * 8);
        #pragma unroll
        for (int e = 0; e < 8; ++e) qr[c * 8 + e] = bf2f(((const unsigned short*)&q8)[e]);
    }
    float acc[DH];
    #pragma unroll
    for (int d = 0; d < DH; ++d) acc[d] = 0.f;
    float mval = -1e30f, lval = 0.f;

    float* Ks = smem + w * 4096;
    float* Vs = Ks + 2048;
    const unsigned short* kbase = k + (size_t)b * TT * DD + h * DH;
    const unsigned short* vbase = v + (size_t)b * TT * DD + h * DH;

    const int nt = (CAUSAL ? (q0 + 64) : TT) >> 5;
    for (int t = w; t < nt; t += 4) {
        const int kt = t << 5;
        #pragma unroll
        for (int ii = 0; ii < 4; ++ii) {
            const int r = (ii << 3) + (lane >> 3);
            const int e0 = (lane & 7) << 3;
            const bf16x8 k8 = *(const bf16x8*)(kbase + (size_t)(kt + r) * DD + e0);
            const bf16x8 v8 = *(const bf16x8*)(vbase + (size_t)(kt + r) * DD + e0);
            float* kd = Ks + r * 64 + e0;
            float* vd = Vs + r * 64 + e0;
            #pragma unroll
            for (int e = 0; e < 8; ++e) {
                kd[e] = bf2f(((const unsigned short*)&k8)[e]);
                vd[e] = bf2f(((const unsigned short*)&v8)[e]);
            }
        }
        __builtin_amdgcn_sched_barrier(0);
        float sv[32];
        #pragma unroll
        for (int j = 0; j < 32; ++j) {
            float s = 0.f;
            #pragma unroll
            for (int d = 0; d < DH; ++d) s += qr[d] * Ks[j * 64 + d];
            if (CAUSAL) s = (kt + j <= row) ? s : -1e30f;
            sv[j] = s;
        }
        float mt = mval;
        #pragma unroll
        for (int j = 0; j < 32; ++j) mt = fmaxf(mt, sv[j]);
        const float sc = __expf(mval - mt);
        lval *= sc;
        #pragma unroll
        for (int d = 0; d < DH; ++d) acc[d] *= sc;
        #pragma unroll
        for (int j = 0; j < 32; ++j) {
            const float p = __expf(sv[j] - mt);
            lval += p;
            #pragma unroll
            for (int d = 0; d < DH; ++d) acc[d] += p * Vs[j * 64 + d];
        }
        mval = mt;
        __builtin_amdgcn_sched_barrier(0);
    }

    __syncthreads();
    float* Crow = smem + (size_t)(w * 64 + lane) * 69;
    #pragma unroll
    for (int d = 0; d < DH; ++d) Crow[d] = acc[d];
    Crow[64] = mval;
    Crow[65] = lval;
    __syncthreads();

    {
        const int r = tid >> 2, dq = tid & 3;
        float mw[4], lw[4];
        #pragma unroll
        for (int u = 0; u < 4; ++u) {
            mw[u] = smem[(size_t)(u * 64 + r) * 69 + 64];
            lw[u] = smem[(size_t)(u * 64 + r) * 69 + 65];
        }
        const float M = fmaxf(fmaxf(mw[0], mw[1]), fmaxf(mw[2], mw[3]));
        float sc[4], L = 0.f;
        #pragma unroll
        for (int u = 0; u < 4; ++u) { sc[u] = __expf(mw[u] - M); L += sc[u] * lw[u]; }
        const float invL = 1.f / L;
        unsigned short* op = out + ((size_t)(b * TT + q0 + r) * DD) + h * DH + dq * 16;
        #pragma unroll
        for (int d = 0; d < 16; ++d) {
            float o = 0.f;
            #pragma unroll
            for (int u = 0; u < 4; ++u) o += sc[u] * smem[(size_t)(u * 64 + r) * 69 + dq * 16 + d];
            op[d] = f2bf(o * invL);
        }
        if (STOREML && (!DUAL || which == 1) && dq == 0) {
            const size_t mi = (((size_t)b * HH + h) * TT + q0 + r) * 2;
            ml[mi] = M;
            ml[mi + 1] = L;
        }
    }
}

// ---------------------------------------------------------------------------
// bf16 elementwise add (attn_a + attn_c -> attn_sum).
// ---------------------------------------------------------------------------
__global__ __launch_bounds__(256) void sum_bf16_kernel(const unsigned short* __restrict__ a,
                                                       const unsigned short* __restrict__ b,
                                                       unsigned short* __restrict__ o, int n)
{
    const int i = (blockIdx.x * 256 + threadIdx.x) * 8;
    if (i >= n) return;
    const bf16x8 av = *(const bf16x8*)(a + i);
    const bf16x8 bv = *(const bf16x8*)(b + i);
    unsigned short ov[8];
    #pragma unroll
    for (int e = 0; e < 8; ++e)
        ov[e] = f2bf(bf2f(((const unsigned short*)&av)[e]) + bf2f(((const unsigned short*)&bv)[e]));
    *(bf16x8*)(o + i) = *(bf16x8*)ov;
}

// ---------------------------------------------------------------------------
// avg via MFMA: avg[b,q,kt] (+)= (1/(H*L)) * sum_h exp(q.kc - m)/l
// One wave per (64q x 64kt) tile; loops 8 heads; q/kc tiles staged via
// swizzled global_load_lds; (m, 1/l) staged once.
// ---------------------------------------------------------------------------
__global__ __launch_bounds__(64) void avg_mfma_kernel(const unsigned short* __restrict__ qm,
                                                      const unsigned short* __restrict__ kcm,
                                                      const float* __restrict__ ml,
                                                      float* __restrict__ avg, int first)
{
    __shared__ __align__(16) unsigned char ldsQ[8192];
    __shared__ __align__(16) unsigned char ldsK[8192];
    __shared__ float sM[8][64];
    __shared__ float sIL[8][64];
    const int lane = threadIdx.x;
    const int kt0 = blockIdx.x << 6, q0 = blockIdx.y << 6, b = blockIdx.z;

    #pragma unroll
    for (int h = 0; h < 8; ++h) {
        const float* mp = ml + (((size_t)(b * HH + h) * TT) + q0 + lane) * 2;
        sM[h][lane] = mp[0];
        sIL[h][lane] = 1.f / mp[1];
    }

    float avac[4][4][4] = {};
    const int akey = (lane & 7) << 4;
    const int frow = lane & 15;
    const int kq = (lane >> 4) << 4;
    const int crow0 = (lane >> 4) << 2;

    for (int h = 0; h < 8; ++h) {
        __syncthreads();
        #pragma unroll
        for (int c = 0; c < 8; ++c) {
            const int o = (c << 10) + (lane << 4);
            const int row = o >> 7;
            const int colb = (o & 127) ^ ((row & 7) << 4);
            gload16((const char*)qm + ((size_t)(b * TT + q0 + row) * DD + h * DH) * 2 + colb,
                    ldsQ + (c << 10));
            gload16((const char*)kcm + ((size_t)(b * TT + kt0 + row) * DD + h * DH) * 2 + colb,
                    ldsK + (c << 10));
        }
        asm volatile("s_waitcnt vmcnt(0)" ::: "memory");
        __syncthreads();
        f32x4 s[4][4] = {};
        #pragma unroll
        for (int kk = 0; kk < 2; ++kk) {
            bf16x8 qv[4], kv[4];
            #pragma unroll
            for (int i = 0; i < 4; ++i) {
                qv[i] = *(const bf16x8*)(ldsQ + (((i << 4) + frow) << 7) + (((kk << 6) + kq) ^ akey));
                kv[i] = *(const bf16x8*)(ldsK + (((i << 4) + frow) << 7) + (((kk << 6) + kq) ^ akey));
            }
            #pragma unroll
            for (int i = 0; i < 4; ++i)
                #pragma unroll
                for (int j = 0; j < 4; ++j)
                    s[i][j] = __builtin_amdgcn_mfma_f32_16x16x32_bf16(qv[i], kv[j], s[i][j], 0, 0, 0);
        }
        #pragma unroll
        for (int i = 0; i < 4; ++i)
            #pragma unroll
            for (int j = 0; j < 4; ++j)
                #pragma unroll
                for (int r = 0; r < 4; ++r) {
                    const int qr = (i << 4) + crow0 + r;
                    avac[i][j][r] += __expf(s[i][j][r] - sM[h][qr]) * sIL[h][qr];
                }
    }

    float* dst = avg + ((size_t)b * TT + q0) * TT + kt0;
    #pragma unroll
    for (int i = 0; i < 4; ++i)
        #pragma unroll
        for (int j = 0; j < 4; ++j)
            #pragma unroll
            for (int r = 0; r < 4; ++r) {
                const int qr = (i << 4) + crow0 + r;
                const int kc = (j << 4) + (lane & 15);
                const float v = avac[i][j][r] * (1.f / (HH * LL));
                float* p = dst + (size_t)qr * TT + kc;
                *p = first ? v : (*p + v);
            }
}

// ---------------------------------------------------------------------------
extern "C" void kernel_launch(void* const* d_in, const int* in_sizes, int n_in,
                              void* d_out, int out_size, void* d_ws, size_t ws_size,
                              hipStream_t stream)
{
    const float* x_in   = (const float*)d_in[0];
    const float* enc_a  = (const float*)d_in[1];
    const float* enc_c  = (const float*)d_in[2];
    const float* sa_wq0 = (const float*)d_in[3];
    const float* sa_wk0 = (const float*)d_in[4];
    const float* sa_wv0 = (const float*)d_in[5];
    const float* sa_wo0 = (const float*)d_in[6];
    const float* ed_wq0 = (const float*)d_in[7];
    const float* ed_wk0 = (const float*)d_in[8];
    const float* ed_wv0 = (const float*)d_in[9];
    const float* ed_wo0 = (const float*)d_in[10];
    const float* ffn_w10 = (const float*)d_in[11];
    const float* ffn_w20 = (const float*)d_in[12];
    const float* ln1_g0 = (const float*)d_in[13];
    const float* ln1_b0 = (const float*)d_in[14];
    const float* ln2_g0 = (const float*)d_in[15];
    const float* ln2_b0 = (const float*)d_in[16];
    const float* ln3_g0 = (const float*)d_in[17];
    const float* ln3_b0 = (const float*)d_in[18];
    const float* out_g  = (const float*)d_in[19];
    const float* out_b  = (const float*)d_in[20];

    const size_t NTD = (size_t)MM * DD;       // 2,097,152
    const size_t MB = 1u << 20;
    char* W = (char*)d_ws;
    float*          x_buf   = (float*)(W);                   // 8 MB
    unsigned short* h_bf    = (unsigned short*)(W + 8 * MB); // 4 MB
    unsigned short* q_bf    = (unsigned short*)(W + 12 * MB);
    unsigned short* k1_bf   = (unsigned short*)(W + 16 * MB);
    unsigned short* v1_bf   = (unsigned short*)(W + 20 * MB);
    unsigned short* k2_bf   = (unsigned short*)(W + 24 * MB);
    unsigned short* v2_bf   = (unsigned short*)(W + 28 * MB);
    unsigned short* attnA   = (unsigned short*)(W + 32 * MB);
    unsigned short* attnC   = (unsigned short*)(W + 36 * MB);
    float*          ml_buf  = (float*)(W + 40 * MB);         // 256 KB
    unsigned short* encA_bf = (unsigned short*)(W + 41 * MB);
    unsigned short* encC_bf = (unsigned short*)(W + 45 * MB);
    unsigned short* wbf     = (unsigned short*)(W + 49 * MB); // 16.8 MB
    unsigned short* ffn_bf  = q_bf;   // alias (16 MB spans q..v2, all dead in FFN)
    unsigned short* attnS   = h_bf;   // alias (h dead after projections)

    unsigned short* w1t = wbf + (size_t)16 * DD * DD;
    unsigned short* w2t = w1t + (size_t)2 * DD * FF;
    auto wd = [&](int l, int which) { return wbf + ((size_t)(l * 8 + which)) * DD * DD; };

    float* x_out   = (float*)d_out;
    float* avg_out = (float*)d_out + NTD;

    hipMemcpyAsync(x_buf, x_in, NTD * sizeof(float), hipMemcpyDeviceToDevice, stream);

    // ---- setup: weight transpose+convert, enc convert ----
    {
        CvtJobs16 J{};
        const float* srcs[8] = {sa_wq0, sa_wk0, sa_wv0, sa_wo0, ed_wq0, ed_wk0, ed_wv0, ed_wo0};
        for (int l = 0; l < LL; ++l)
            for (int t = 0; t < 8; ++t) {
                J.j[l * 8 + t].s = srcs[t] + (size_t)l * DD * DD;
                J.j[l * 8 + t].d = wd(l, t);
            }
        cvtT_kernel<<<dim3(DD / 32, DD / 32, 16), 256, 0, stream>>>(J, DD, DD);
    }
    {
        CvtJobs16 J{};
        for (int l = 0; l < LL; ++l) { J.j[l].s = ffn_w10 + (size_t)l * DD * FF; J.j[l].d = w1t + (size_t)l * FF * DD; }
        cvtT_kernel<<<dim3(FF / 32, DD / 32, 2), 256, 0, stream>>>(J, DD, FF);
    }
    {
        CvtJobs16 J{};
        for (int l = 0; l < LL; ++l) { J.j[l].s = ffn_w20 + (size_t)l * FF * DD; J.j[l].d = w2t + (size_t)l * DD * FF; }
        cvtT_kernel<<<dim3(DD / 32, FF / 32, 2), 256, 0, stream>>>(J, FF, DD);
    }
    cvt_kernel<<<NTD / 8 / 256, 256, 0, stream>>>(enc_a, encA_bf, (int)NTD);
    cvt_kernel<<<NTD / 8 / 256, 256, 0, stream>>>(enc_c, encC_bf, (int)NTD);

    const dim3 gemmDDg(DD / 128, MM / 128);   // (4, 32)
    const dim3 flashSelfG(TT / 64, HH, BB);
    const dim3 flashCrossG(TT / 64, HH, BB * 2);
    const dim3 avgG(TT / 64, TT / 64, BB);
    const float qscale = 0.125f;

    for (int i = 0; i < LL; ++i) {
        const size_t fOff = (size_t)i * DD * FF;
        const size_t lOff = (size_t)i * DD;

        // --- self attention ---
        ln_kernel<true><<<MM, 256, 0, stream>>>(x_buf, ln1_g0 + lOff, ln1_b0 + lOff, h_bf);
        {
            GemmJobs6 J{};
            J.j[0] = {h_bf, wd(i, 0), nullptr, nullptr, q_bf, qscale, 0};
            J.j[1] = {h_bf, wd(i, 1), nullptr, nullptr, k1_bf, 1.f, 0};
            J.j[2] = {h_bf, wd(i, 2), nullptr, nullptr, v1_bf, 1.f, 0};
            gemm_mfma<<<dim3(DD / 128, MM / 128, 3), 256, 0, stream>>>(J, MM, DD, DD);
        }
        flash4_kernel<true, false, false><<<flashSelfG, 256, 0, stream>>>(
            q_bf, k1_bf, v1_bf, nullptr, nullptr, attnA, nullptr, nullptr);
        {
            GemmJobs6 J{};
            J.j[0] = {attnA, wd(i, 3), x_buf, x_buf, nullptr, 1.f, 0};
            gemm_mfma<<<dim3(DD / 128, MM / 128, 1), 256, 0, stream>>>(J, MM, DD, DD);
        }

        // --- cross attention (enc_a + enc_c, shared weights) ---
        ln_kernel<true><<<MM, 256, 0, stream>>>(x_buf, ln2_g0 + lOff, ln2_b0 + lOff, h_bf);
        {
            GemmJobs6 J{};
            J.j[0] = {h_bf,    wd(i, 4), nullptr, nullptr, q_bf, qscale, 0};
            J.j[1] = {encA_bf, wd(i, 5), nullptr, nullptr, k1_bf, 1.f, 0};
            J.j[2] = {encA_bf, wd(i, 6), nullptr, nullptr, v1_bf, 1.f, 0};
            J.j[3] = {encC_bf, wd(i, 5), nullptr, nullptr, k2_bf, 1.f, 0};
            J.j[4] = {encC_bf, wd(i, 6), nullptr, nullptr, v2_bf, 1.f, 0};
            gemm_mfma<<<dim3(DD / 128, MM / 128, 5), 256, 0, stream>>>(J, MM, DD, DD);
        }
        flash4_kernel<false, true, true><<<flashCrossG, 256, 0, stream>>>(
            q_bf, k1_bf, v1_bf, k2_bf, v2_bf, attnA, attnC, ml_buf);
        sum_bf16_kernel<<<NTD / 8 / 256, 256, 0, stream>>>(attnA, attnC, attnS, (int)NTD);
        avg_mfma_kernel<<<avgG, 64, 0, stream>>>(q_bf, k2_bf, ml_buf, avg_out, (i == 0) ? 1 : 0);
        {
            GemmJobs6 J{};
            J.j[0] = {attnS, wd(i, 7), x_buf, x_buf, nullptr, 1.f, 0};
            gemm_mfma<<<dim3(DD / 128, MM / 128, 1), 256, 0, stream>>>(J, MM, DD, DD);
        }

        // --- FFN ---
        ln_kernel<true><<<MM, 256, 0, stream>>>(x_buf, ln3_g0 + lOff, ln3_b0 + lOff, h_bf);
        {
            GemmJobs6 J{};
            J.j[0] = {h_bf, w1t + fOff, nullptr, nullptr, ffn_bf, 1.f, 1};
            gemm_mfma<<<dim3(FF / 128, MM / 128, 1), 256, 0, stream>>>(J, MM, FF, DD);
        }
        {
            GemmJobs6 J{};
            J.j[0] = {ffn_bf, w2t + fOff, x_buf, x_buf, nullptr, 1.f, 0};
            gemm_mfma<<<dim3(DD / 128, MM / 128, 1), 256, 0, stream>>>(J, MM, DD, FF);
        }
    }

    ln_kernel<false><<<MM, 256, 0, stream>>>(x_buf, out_g, out_b, x_out);
}

// Round 4
// 1393.072 us; speedup vs baseline: 10.8503x; 2.7113x over previous
//
#include <hip/hip_runtime.h>
#include <hip/hip_bf16.h>

// Problem dims (fixed by reference setup_inputs)
#define BB 2
#define TT 2048
#define DD 512
#define FF 2048
#define HH 8
#define DH 64
#define LL 2
#define MM (BB*TT)   // 4096 rows

typedef __attribute__((ext_vector_type(8))) short bf16x8;
typedef __attribute__((ext_vector_type(4))) float f32x4;

__device__ __forceinline__ float bf2f(unsigned short u) {
    return __uint_as_float(((unsigned int)u) << 16);
}
__device__ __forceinline__ unsigned short f2bf(float f) {
    unsigned int u = __float_as_uint(f);
    u += 0x7fffu + ((u >> 16) & 1u);   // round-to-nearest-even
    return (unsigned short)(u >> 16);
}
__device__ __forceinline__ void gload16(const void* g, void* l) {
    __builtin_amdgcn_global_load_lds((__attribute__((address_space(1))) void*)g,
                                     (__attribute__((address_space(3))) void*)l, 16, 0, 0);
}

// ---------------------------------------------------------------------------
// LayerNorm: one block (256 threads) per row of 512 floats. bf16 or f32 out.
// ---------------------------------------------------------------------------
template<bool BF16OUT>
__global__ __launch_bounds__(256) void ln_kernel(const float* __restrict__ x,
                                                 const float* __restrict__ g,
                                                 const float* __restrict__ b,
                                                 void* __restrict__ out)
{
    const int row = blockIdx.x;
    const int tid = threadIdx.x;
    const float2 v = ((const float2*)(x + (size_t)row * DD))[tid];
    float s = v.x + v.y;
    float q = v.x * v.x + v.y * v.y;
    #pragma unroll
    for (int off = 32; off; off >>= 1) {
        s += __shfl_down(s, off);
        q += __shfl_down(q, off);
    }
    __shared__ float ss[4], qq[4];
    const int wid = tid >> 6;
    if ((tid & 63) == 0) { ss[wid] = s; qq[wid] = q; }
    __syncthreads();
    s = ss[0] + ss[1] + ss[2] + ss[3];
    q = qq[0] + qq[1] + qq[2] + qq[3];
    const float mean = s * (1.0f / DD);
    const float var = q * (1.0f / DD) - mean * mean;
    const float inv = rsqrtf(var + 1e-6f);
    const float2 gg = ((const float2*)g)[tid];
    const float2 bb = ((const float2*)b)[tid];
    const float ox = gg.x * (v.x - mean) * inv + bb.x;
    const float oy = gg.y * (v.y - mean) * inv + bb.y;
    if (BF16OUT) {
        const unsigned int pk = (unsigned int)f2bf(ox) | ((unsigned int)f2bf(oy) << 16);
        ((unsigned int*)((unsigned short*)out + (size_t)row * DD))[tid] = pk;
    } else {
        float2 o; o.x = ox; o.y = oy;
        ((float2*)((float*)out + (size_t)row * DD))[tid] = o;
    }
}

// ---------------------------------------------------------------------------
// fp32 -> bf16 elementwise (enc inputs). n multiple of 2048.
// ---------------------------------------------------------------------------
__global__ __launch_bounds__(256) void cvt_kernel(const float* __restrict__ src,
                                                  unsigned short* __restrict__ dst, int n)
{
    const int i = (blockIdx.x * 256 + threadIdx.x) * 8;
    if (i >= n) return;
    const float4 a = *(const float4*)(src + i);
    const float4 b = *(const float4*)(src + i + 4);
    unsigned short o[8];
    o[0] = f2bf(a.x); o[1] = f2bf(a.y); o[2] = f2bf(a.z); o[3] = f2bf(a.w);
    o[4] = f2bf(b.x); o[5] = f2bf(b.y); o[6] = f2bf(b.z); o[7] = f2bf(b.w);
    *(bf16x8*)(dst + i) = *(bf16x8*)o;
}

// ---------------------------------------------------------------------------
// Weight convert + transpose: src fp32 [K][N] -> dst bf16 [N][K]. 32x32 tiles.
// ---------------------------------------------------------------------------
struct CvtJob { const float* s; unsigned short* d; };
struct CvtJobs16 { CvtJob j[16]; };

__global__ __launch_bounds__(256) void cvtT_kernel(CvtJobs16 P, int K, int N)
{
    __shared__ float t[32][33];
    const CvtJob jb = P.j[blockIdx.z];
    const int tx = threadIdx.x & 31, ty = threadIdx.x >> 5;
    const int gk = blockIdx.y << 5, gn = blockIdx.x << 5;
    #pragma unroll
    for (int i = 0; i < 4; ++i)
        t[ty + i * 8][tx] = jb.s[(size_t)(gk + ty + i * 8) * N + gn + tx];
    __syncthreads();
    #pragma unroll
    for (int i = 0; i < 4; ++i)
        jb.d[(size_t)(gn + ty + i * 8) * K + gk + tx] = f2bf(t[tx][ty + i * 8]);
}

// ---------------------------------------------------------------------------
// bf16 MFMA GEMM: C[M,N] = scale * A[M,K] @ Wt[N,K]^T (+res fp32) (ReLU opt).
// 128x128 tile, BK=64, 256 threads = 4 waves (2x2 of 64x64).
// ---------------------------------------------------------------------------
struct GemmJob {
    const unsigned short* A;
    const unsigned short* Wt;
    const float* res;
    float* Cf;
    unsigned short* Cb;
    float scale;
    int relu;
};
struct GemmJobs6 { GemmJob j[6]; };

__global__ __launch_bounds__(256, 2) void gemm_mfma(GemmJobs6 P, int M, int N, int K)
{
    __shared__ __align__(16) unsigned char lds[32768];   // A: 0..16K, B: 16K..32K
    const GemmJob jb = P.j[blockIdx.z];
    const int tid = threadIdx.x, lane = tid & 63, w = tid >> 6;
    const int bn = blockIdx.x << 7, bm = blockIdx.y << 7;
    const int wr = (w >> 1) << 6, wc = (w & 1) << 6;
    const size_t strA = (size_t)K * 2;

    f32x4 acc[4][4] = {};
    const int akey = (lane & 7) << 4;
    const int frow = lane & 15;
    const int kq = (lane >> 4) << 4;

    for (int kt = 0; kt < K; kt += 64) {
        __syncthreads();
        #pragma unroll
        for (int c = 0; c < 4; ++c) {
            const int q = c * 4 + w;
            const int o = (q << 10) + (lane << 4);
            const int row = o >> 7;
            const int colb = (o & 127) ^ ((row & 7) << 4);
            gload16((const char*)jb.A + (size_t)(bm + row) * strA + kt * 2 + colb,
                    lds + (q << 10));
            gload16((const char*)jb.Wt + (size_t)(bn + row) * strA + kt * 2 + colb,
                    lds + 16384 + (q << 10));
        }
        asm volatile("s_waitcnt vmcnt(0)" ::: "memory");
        __syncthreads();
        #pragma unroll
        for (int kk = 0; kk < 2; ++kk) {
            bf16x8 av[4], bv[4];
            #pragma unroll
            for (int i = 0; i < 4; ++i) {
                const int rA = wr + (i << 4) + frow;
                av[i] = *(const bf16x8*)(lds + (rA << 7) + ((((kk << 6) + kq)) ^ akey));
                const int rB = wc + (i << 4) + frow;
                bv[i] = *(const bf16x8*)(lds + 16384 + (rB << 7) + ((((kk << 6) + kq)) ^ akey));
            }
            #pragma unroll
            for (int i = 0; i < 4; ++i)
                #pragma unroll
                for (int j = 0; j < 4; ++j)
                    acc[i][j] = __builtin_amdgcn_mfma_f32_16x16x32_bf16(av[i], bv[j], acc[i][j], 0, 0, 0);
        }
    }

    const int crow0 = (lane >> 4) << 2;
    const int ccol = lane & 15;
    #pragma unroll
    for (int i = 0; i < 4; ++i) {
        #pragma unroll
        for (int j = 0; j < 4; ++j) {
            #pragma unroll
            for (int r = 0; r < 4; ++r) {
                const int gm = bm + wr + (i << 4) + crow0 + r;
                const int gn = bn + wc + (j << 4) + ccol;
                float v = acc[i][j][r] * jb.scale;
                if (jb.relu) v = fmaxf(v, 0.f);
                const size_t idx = (size_t)gm * N + gn;
                if (jb.res) v += jb.res[idx];
                if (jb.Cf) jb.Cf[idx] = v;
                if (jb.Cb) jb.Cb[idx] = f2bf(v);
            }
        }
    }
}

// ---------------------------------------------------------------------------
// MFMA flash attention. Block = 4 waves, 64 q-rows shared, KV-split (each
// wave does a strided 1/4 of the 64-row KV tiles into private 16KB LDS).
// Swapped QK^T: S^T = mfma(K,Q) -> softmax is per-lane-column (4 (m,l)/lane);
// P packs 4 consecutive k per ds_write_b64 into row-major P[q][k] (= PV's
// A-frag layout). V staged transposed (XOR-swizzled). f32 merge at end.
// ---------------------------------------------------------------------------
template<bool CAUSAL, bool DUAL, bool STOREML>
__global__ __launch_bounds__(256, 2) void flash_mfma(
    const unsigned short* __restrict__ q,
    const unsigned short* __restrict__ ka, const unsigned short* __restrict__ va,
    const unsigned short* __restrict__ kc, const unsigned short* __restrict__ vc,
    unsigned short* __restrict__ outa, unsigned short* __restrict__ outc,
    float* __restrict__ ml)
{
    // staging: wave w: K/P at w*16384 (8KB), Vt at w*16384+8192 (8KB) -> 64KB
    // sScale: 65536 + w*256 (1KB total)
    // merge (aliased after barrier): O at w*17408 (64x68 f32), m at 69632+w*256,
    // l at 70656+w*256 -> 71680 total
    __shared__ __align__(16) char lds[71680];
    const int tid = threadIdx.x;
    const int lane = tid & 63, w = tid >> 6;
    const int g = lane >> 4, c = lane & 15;
    const int kq16 = g << 4;                 // 16B k-slice offset per lane quarter
    const int q0 = blockIdx.x << 6;
    const int h = blockIdx.y;
    int b = blockIdx.z;
    int which = 0;
    if (DUAL) { which = b & 1; b >>= 1; }
    const unsigned short* k = (DUAL && which) ? kc : ka;
    const unsigned short* v = (DUAL && which) ? vc : va;
    unsigned short* out = (DUAL && which) ? outc : outa;

    char* myK = lds + w * 16384;             // K tile, later aliased by P
    char* myV = myK + 8192;                  // Vt tile
    float* mySc = (float*)(lds + 65536 + w * 256);

    // Q fragments (B-operand): Qf[j][kk] = Q[q0 + j*16 + c][kk*32 + g*8 ..+7]
    bf16x8 Qf[4][2];
    {
        const unsigned short* qg = q + (size_t)(b * TT + q0) * DD + h * DH;
        #pragma unroll
        for (int j = 0; j < 4; ++j)
            #pragma unroll
            for (int kk = 0; kk < 2; ++kk)
                Qf[j][kk] = *(const bf16x8*)(qg + (size_t)((j << 4) + c) * DD + (kk << 5) + (g << 3));
    }

    const char* kbase = (const char*)(k + (size_t)b * TT * DD + h * DH);
    const unsigned short* vbase = v + (size_t)b * TT * DD + h * DH;

    f32x4 O[4][4] = {};
    float m[4], l[4];
    #pragma unroll
    for (int j = 0; j < 4; ++j) { m[j] = -1e30f; l[j] = 0.f; }

    const int nt = (CAUSAL ? (q0 + 64) : TT) >> 6;   // 64-row KV tiles
    for (int t = w; t < nt; t += 4) {
        const int kt = t << 6;
        // ---- ensure previous tile's P/Vt LDS reads are done, then stage ----
        asm volatile("s_waitcnt lgkmcnt(0)" ::: "memory");
        __builtin_amdgcn_sched_barrier(0);
        // K tile via global_load_lds, pre-swizzled source (key (row&7)<<4)
        #pragma unroll
        for (int c8 = 0; c8 < 8; ++c8) {
            const int o = (c8 << 10) + (lane << 4);
            const int krow = o >> 7;
            const int colb = (o & 127) ^ ((krow & 7) << 4);
            gload16(kbase + (size_t)(kt + krow) * (DD * 2) + colb, myK + (c8 << 10));
        }
        // Vt tile (transposed), reg-staged, key ((d>>3)^d)&7 << 4
        #pragma unroll
        for (int ii = 0; ii < 8; ++ii) {
            const int kl = (ii << 3) + (lane >> 3);
            const int d0 = (lane & 7) << 3;
            const bf16x8 v8 = *(const bf16x8*)(vbase + (size_t)(kt + kl) * DD + d0);
            #pragma unroll
            for (int e = 0; e < 8; ++e) {
                const int d = d0 + e;
                const int key = (((d >> 3) ^ d) & 7) << 4;
                *(unsigned short*)(myV + (((d << 7) + (kl << 1)) ^ key)) =
                    ((const unsigned short*)&v8)[e];
            }
        }
        asm volatile("s_waitcnt vmcnt(0)" ::: "memory");
        __builtin_amdgcn_sched_barrier(0);

        // ---- QK^T (swapped): s[i][j] = S^T rows k(i), cols q(j) ----
        f32x4 s[4][4] = {};
        #pragma unroll
        for (int kk = 0; kk < 2; ++kk) {
            bf16x8 av[4];
            #pragma unroll
            for (int i = 0; i < 4; ++i) {
                const int r = (i << 4) + c;
                av[i] = *(const bf16x8*)(myK + (r << 7) + (((kk << 6) + kq16) ^ ((r & 7) << 4)));
            }
            #pragma unroll
            for (int i = 0; i < 4; ++i)
                #pragma unroll
                for (int j = 0; j < 4; ++j)
                    s[i][j] = __builtin_amdgcn_mfma_f32_16x16x32_bf16(av[i], Qf[j][kk], s[i][j], 0, 0, 0);
        }

        if (CAUSAL && kt == q0) {   // diagonal tile mask: keep k_abs <= q_abs
            #pragma unroll
            for (int i = 0; i < 4; ++i)
                #pragma unroll
                for (int j = 0; j < 4; ++j)
                    #pragma unroll
                    for (int r = 0; r < 4; ++r) {
                        const int kAbs = (i << 4) + (g << 2) + r;
                        const int qAbs = (j << 4) + c;
                        if (kAbs > qAbs) s[i][j][r] = -1e30f;
                    }
        }

        // ---- online softmax per q-column ----
        float scol[4];
        #pragma unroll
        for (int j = 0; j < 4; ++j) {
            float mx = -1e30f;
            #pragma unroll
            for (int i = 0; i < 4; ++i)
                #pragma unroll
                for (int r = 0; r < 4; ++r) mx = fmaxf(mx, s[i][j][r]);
            mx = fmaxf(mx, __shfl_xor(mx, 16));
            mx = fmaxf(mx, __shfl_xor(mx, 32));
            const float mn = fmaxf(m[j], mx);
            scol[j] = __expf(m[j] - mn);
            float ps = 0.f;
            #pragma unroll
            for (int i = 0; i < 4; ++i)
                #pragma unroll
                for (int r = 0; r < 4; ++r) {
                    const float p = __expf(s[i][j][r] - mn);
                    s[i][j][r] = p;
                    ps += p;
                }
            ps += __shfl_xor(ps, 16);
            ps += __shfl_xor(ps, 32);
            l[j] = l[j] * scol[j] + ps;
            m[j] = mn;
        }

        // ---- write P (bf16) into myK alias: P[q][k], key (q&7)<<4 ----
        #pragma unroll
        for (int i = 0; i < 4; ++i)
            #pragma unroll
            for (int j = 0; j < 4; ++j) {
                uint2 pk;
                pk.x = (unsigned int)f2bf(s[i][j][0]) | ((unsigned int)f2bf(s[i][j][1]) << 16);
                pk.y = (unsigned int)f2bf(s[i][j][2]) | ((unsigned int)f2bf(s[i][j][3]) << 16);
                const int qq = (j << 4) + c;
                const int kloc = (i << 4) + (g << 2);
                *(uint2*)(myK + (((qq << 7) + (kloc << 1)) ^ ((qq & 7) << 4))) = pk;
            }

        // ---- O rescale (per-row scale broadcast via LDS) ----
        if (g == 0) {
            #pragma unroll
            for (int j = 0; j < 4; ++j) mySc[(j << 4) + c] = scol[j];
        }
        #pragma unroll
        for (int i = 0; i < 4; ++i) {
            const f32x4 sc4 = *(const f32x4*)(mySc + (i << 4) + (g << 2));
            #pragma unroll
            for (int j = 0; j < 4; ++j)
                #pragma unroll
                for (int r = 0; r < 4; ++r) O[i][j][r] *= sc4[r];
        }

        // ---- PV: O += P @ Vt^T ----
        #pragma unroll
        for (int kk = 0; kk < 2; ++kk) {
            bf16x8 pa[4], vb[4];
            #pragma unroll
            for (int i = 0; i < 4; ++i) {
                const int r = (i << 4) + c;
                pa[i] = *(const bf16x8*)(myK + (r << 7) + (((kk << 6) + kq16) ^ ((r & 7) << 4)));
            }
            #pragma unroll
            for (int j = 0; j < 4; ++j) {
                const int d = (j << 4) + c;
                const int key = (((d >> 3) ^ d) & 7) << 4;
                vb[j] = *(const bf16x8*)(myV + (d << 7) + (((kk << 6) + kq16) ^ key));
            }
            #pragma unroll
            for (int i = 0; i < 4; ++i)
                #pragma unroll
                for (int j = 0; j < 4; ++j)
                    O[i][j] = __builtin_amdgcn_mfma_f32_16x16x32_bf16(pa[i], vb[j], O[i][j], 0, 0, 0);
        }
    }

    // ---- merge 4 wave-partials ----
    __syncthreads();   // all staging reads done; safe to alias merge region
    float* mO = (float*)(lds + w * 17408);
    float* mM = (float*)(lds + 69632 + w * 256);
    float* mL = (float*)(lds + 70656 + w * 256);
    #pragma unroll
    for (int i = 0; i < 4; ++i)
        #pragma unroll
        for (int j = 0; j < 4; ++j)
            #pragma unroll
            for (int r = 0; r < 4; ++r)
                mO[((i << 4) + (g << 2) + r) * 68 + (j << 4) + c] = O[i][j][r];
    if (g == 0) {
        #pragma unroll
        for (int j = 0; j < 4; ++j) { mM[(j << 4) + c] = m[j]; mL[(j << 4) + c] = l[j]; }
    }
    __syncthreads();

    {
        const int r = tid >> 2, dq = tid & 3;
        float mw[4], lw[4];
        #pragma unroll
        for (int u = 0; u < 4; ++u) {
            mw[u] = ((const float*)(lds + 69632 + u * 256))[r];
            lw[u] = ((const float*)(lds + 70656 + u * 256))[r];
        }
        const float M = fmaxf(fmaxf(mw[0], mw[1]), fmaxf(mw[2], mw[3]));
        float sc[4], L = 0.f;
        #pragma unroll
        for (int u = 0; u < 4; ++u) { sc[u] = __expf(mw[u] - M); L += sc[u] * lw[u]; }
        const float invL = 1.f / L;
        unsigned short ov[16];
        #pragma unroll
        for (int dd = 0; dd < 16; ++dd) {
            float o = 0.f;
            #pragma unroll
            for (int u = 0; u < 4; ++u)
                o += sc[u] * ((const float*)(lds + u * 17408))[r * 68 + (dq << 4) + dd];
            ov[dd] = f2bf(o * invL);
        }
        unsigned short* op = out + (size_t)(b * TT + q0 + r) * DD + h * DH + (dq << 4);
        *(bf16x8*)op = *(bf16x8*)ov;
        *(bf16x8*)(op + 8) = *(bf16x8*)(ov + 8);
        if (STOREML && (!DUAL || which == 1) && dq == 0) {
            const size_t mi = (((size_t)b * HH + h) * TT + q0 + r) * 2;
            ml[mi] = M;
            ml[mi + 1] = L;
        }
    }
}

// ---------------------------------------------------------------------------
// bf16 elementwise add (attn_a + attn_c -> attn_sum).
// ---------------------------------------------------------------------------
__global__ __launch_bounds__(256) void sum_bf16_kernel(const unsigned short* __restrict__ a,
                                                       const unsigned short* __restrict__ b,
                                                       unsigned short* __restrict__ o, int n)
{
    const int i = (blockIdx.x * 256 + threadIdx.x) * 8;
    if (i >= n) return;
    const bf16x8 av = *(const bf16x8*)(a + i);
    const bf16x8 bv = *(const bf16x8*)(b + i);
    unsigned short ov[8];
    #pragma unroll
    for (int e = 0; e < 8; ++e)
        ov[e] = f2bf(bf2f(((const unsigned short*)&av)[e]) + bf2f(((const unsigned short*)&bv)[e]));
    *(bf16x8*)(o + i) = *(bf16x8*)ov;
}

// ---------------------------------------------------------------------------
// avg via MFMA: avg[b,q,kt] (+)= (1/(H*L)) * sum_h exp(q.kc - m)/l
// ---------------------------------------------------------------------------
__global__ __launch_bounds__(64) void avg_mfma_kernel(const unsigned short* __restrict__ qm,
                                                      const unsigned short* __restrict__ kcm,
                                                      const float* __restrict__ ml,
                                                      float* __restrict__ avg, int first)
{
    __shared__ __align__(16) unsigned char ldsQ[8192];
    __shared__ __align__(16) unsigned char ldsK[8192];
    __shared__ float sM[8][64];
    __shared__ float sIL[8][64];
    const int lane = threadIdx.x;
    const int kt0 = blockIdx.x << 6, q0 = blockIdx.y << 6, b = blockIdx.z;

    #pragma unroll
    for (int h = 0; h < 8; ++h) {
        const float* mp = ml + (((size_t)(b * HH + h) * TT) + q0 + lane) * 2;
        sM[h][lane] = mp[0];
        sIL[h][lane] = 1.f / mp[1];
    }

    float avac[4][4][4] = {};
    const int akey = (lane & 7) << 4;
    const int frow = lane & 15;
    const int kq = (lane >> 4) << 4;
    const int crow0 = (lane >> 4) << 2;

    for (int h = 0; h < 8; ++h) {
        __syncthreads();
        #pragma unroll
        for (int c = 0; c < 8; ++c) {
            const int o = (c << 10) + (lane << 4);
            const int row = o >> 7;
            const int colb = (o & 127) ^ ((row & 7) << 4);
            gload16((const char*)qm + ((size_t)(b * TT + q0 + row) * DD + h * DH) * 2 + colb,
                    ldsQ + (c << 10));
            gload16((const char*)kcm + ((size_t)(b * TT + kt0 + row) * DD + h * DH) * 2 + colb,
                    ldsK + (c << 10));
        }
        asm volatile("s_waitcnt vmcnt(0)" ::: "memory");
        __syncthreads();
        f32x4 s[4][4] = {};
        #pragma unroll
        for (int kk = 0; kk < 2; ++kk) {
            bf16x8 qv[4], kv[4];
            #pragma unroll
            for (int i = 0; i < 4; ++i) {
                qv[i] = *(const bf16x8*)(ldsQ + (((i << 4) + frow) << 7) + (((kk << 6) + kq) ^ akey));
                kv[i] = *(const bf16x8*)(ldsK + (((i << 4) + frow) << 7) + (((kk << 6) + kq) ^ akey));
            }
            #pragma unroll
            for (int i = 0; i < 4; ++i)
                #pragma unroll
                for (int j = 0; j < 4; ++j)
                    s[i][j] = __builtin_amdgcn_mfma_f32_16x16x32_bf16(qv[i], kv[j], s[i][j], 0, 0, 0);
        }
        #pragma unroll
        for (int i = 0; i < 4; ++i)
            #pragma unroll
            for (int j = 0; j < 4; ++j)
                #pragma unroll
                for (int r = 0; r < 4; ++r) {
                    const int qr = (i << 4) + crow0 + r;
                    avac[i][j][r] += __expf(s[i][j][r] - sM[h][qr]) * sIL[h][qr];
                }
    }

    float* dst = avg + ((size_t)b * TT + q0) * TT + kt0;
    #pragma unroll
    for (int i = 0; i < 4; ++i)
        #pragma unroll
        for (int j = 0; j < 4; ++j)
            #pragma unroll
            for (int r = 0; r < 4; ++r) {
                const int qr = (i << 4) + crow0 + r;
                const int kc = (j << 4) + (lane & 15);
                const float v = avac[i][j][r] * (1.f / (HH * LL));
                float* p = dst + (size_t)qr * TT + kc;
                *p = first ? v : (*p + v);
            }
}

// ---------------------------------------------------------------------------
extern "C" void kernel_launch(void* const* d_in, const int* in_sizes, int n_in,
                              void* d_out, int out_size, void* d_ws, size_t ws_size,
                              hipStream_t stream)
{
    const float* x_in   = (const float*)d_in[0];
    const float* enc_a  = (const float*)d_in[1];
    const float* enc_c  = (const float*)d_in[2];
    const float* sa_wq0 = (const float*)d_in[3];
    const float* sa_wk0 = (const float*)d_in[4];
    const float* sa_wv0 = (const float*)d_in[5];
    const float* sa_wo0 = (const float*)d_in[6];
    const float* ed_wq0 = (const float*)d_in[7];
    const float* ed_wk0 = (const float*)d_in[8];
    const float* ed_wv0 = (const float*)d_in[9];
    const float* ed_wo0 = (const float*)d_in[10];
    const float* ffn_w10 = (const float*)d_in[11];
    const float* ffn_w20 = (const float*)d_in[12];
    const float* ln1_g0 = (const float*)d_in[13];
    const float* ln1_b0 = (const float*)d_in[14];
    const float* ln2_g0 = (const float*)d_in[15];
    const float* ln2_b0 = (const float*)d_in[16];
    const float* ln3_g0 = (const float*)d_in[17];
    const float* ln3_b0 = (const float*)d_in[18];
    const float* out_g  = (const float*)d_in[19];
    const float* out_b  = (const float*)d_in[20];

    const size_t NTD = (size_t)MM * DD;       // 2,097,152
    const size_t MB = 1u << 20;
    char* W = (char*)d_ws;
    float*          x_buf   = (float*)(W);                   // 8 MB
    unsigned short* h_bf    = (unsigned short*)(W + 8 * MB); // 4 MB
    unsigned short* q_bf    = (unsigned short*)(W + 12 * MB);
    unsigned short* k1_bf   = (unsigned short*)(W + 16 * MB);
    unsigned short* v1_bf   = (unsigned short*)(W + 20 * MB);
    unsigned short* k2_bf   = (unsigned short*)(W + 24 * MB);
    unsigned short* v2_bf   = (unsigned short*)(W + 28 * MB);
    unsigned short* attnA   = (unsigned short*)(W + 32 * MB);
    unsigned short* attnC   = (unsigned short*)(W + 36 * MB);
    float*          ml_buf  = (float*)(W + 40 * MB);         // 256 KB
    unsigned short* encA_bf = (unsigned short*)(W + 41 * MB);
    unsigned short* encC_bf = (unsigned short*)(W + 45 * MB);
    unsigned short* wbf     = (unsigned short*)(W + 49 * MB); // 16.8 MB
    unsigned short* ffn_bf  = q_bf;   // alias (16 MB spans q..v2, all dead in FFN)
    unsigned short* attnS   = h_bf;   // alias (h dead after projections)

    unsigned short* w1t = wbf + (size_t)16 * DD * DD;
    unsigned short* w2t = w1t + (size_t)2 * DD * FF;
    auto wd = [&](int l, int which) { return wbf + ((size_t)(l * 8 + which)) * DD * DD; };

    float* x_out   = (float*)d_out;
    float* avg_out = (float*)d_out + NTD;

    hipMemcpyAsync(x_buf, x_in, NTD * sizeof(float), hipMemcpyDeviceToDevice, stream);

    // ---- setup: weight transpose+convert, enc convert ----
    {
        CvtJobs16 J{};
        const float* srcs[8] = {sa_wq0, sa_wk0, sa_wv0, sa_wo0, ed_wq0, ed_wk0, ed_wv0, ed_wo0};
        for (int l = 0; l < LL; ++l)
            for (int t = 0; t < 8; ++t) {
                J.j[l * 8 + t].s = srcs[t] + (size_t)l * DD * DD;
                J.j[l * 8 + t].d = wd(l, t);
            }
        cvtT_kernel<<<dim3(DD / 32, DD / 32, 16), 256, 0, stream>>>(J, DD, DD);
    }
    {
        CvtJobs16 J{};
        for (int l = 0; l < LL; ++l) { J.j[l].s = ffn_w10 + (size_t)l * DD * FF; J.j[l].d = w1t + (size_t)l * FF * DD; }
        cvtT_kernel<<<dim3(FF / 32, DD / 32, 2), 256, 0, stream>>>(J, DD, FF);
    }
    {
        CvtJobs16 J{};
        for (int l = 0; l < LL; ++l) { J.j[l].s = ffn_w20 + (size_t)l * FF * DD; J.j[l].d = w2t + (size_t)l * DD * FF; }
        cvtT_kernel<<<dim3(DD / 32, FF / 32, 2), 256, 0, stream>>>(J, FF, DD);
    }
    cvt_kernel<<<NTD / 8 / 256, 256, 0, stream>>>(enc_a, encA_bf, (int)NTD);
    cvt_kernel<<<NTD / 8 / 256, 256, 0, stream>>>(enc_c, encC_bf, (int)NTD);

    const dim3 flashSelfG(TT / 64, HH, BB);      // (32, 8, 2)
    const dim3 flashCrossG(TT / 64, HH, BB * 2); // (32, 8, 4)
    const dim3 avgG(TT / 64, TT / 64, BB);       // (32, 32, 2)
    const float qscale = 0.125f;

    for (int i = 0; i < LL; ++i) {
        const size_t fOff = (size_t)i * DD * FF;
        const size_t lOff = (size_t)i * DD;

        // --- self attention ---
        ln_kernel<true><<<MM, 256, 0, stream>>>(x_buf, ln1_g0 + lOff, ln1_b0 + lOff, h_bf);
        {
            GemmJobs6 J{};
            J.j[0] = {h_bf, wd(i, 0), nullptr, nullptr, q_bf, qscale, 0};
            J.j[1] = {h_bf, wd(i, 1), nullptr, nullptr, k1_bf, 1.f, 0};
            J.j[2] = {h_bf, wd(i, 2), nullptr, nullptr, v1_bf, 1.f, 0};
            gemm_mfma<<<dim3(DD / 128, MM / 128, 3), 256, 0, stream>>>(J, MM, DD, DD);
        }
        flash_mfma<true, false, false><<<flashSelfG, 256, 0, stream>>>(
            q_bf, k1_bf, v1_bf, nullptr, nullptr, attnA, nullptr, nullptr);
        {
            GemmJobs6 J{};
            J.j[0] = {attnA, wd(i, 3), x_buf, x_buf, nullptr, 1.f, 0};
            gemm_mfma<<<dim3(DD / 128, MM / 128, 1), 256, 0, stream>>>(J, MM, DD, DD);
        }

        // --- cross attention (enc_a + enc_c, shared weights) ---
        ln_kernel<true><<<MM, 256, 0, stream>>>(x_buf, ln2_g0 + lOff, ln2_b0 + lOff, h_bf);
        {
            GemmJobs6 J{};
            J.j[0] = {h_bf,    wd(i, 4), nullptr, nullptr, q_bf, qscale, 0};
            J.j[1] = {encA_bf, wd(i, 5), nullptr, nullptr, k1_bf, 1.f, 0};
            J.j[2] = {encA_bf, wd(i, 6), nullptr, nullptr, v1_bf, 1.f, 0};
            J.j[3] = {encC_bf, wd(i, 5), nullptr, nullptr, k2_bf, 1.f, 0};
            J.j[4] = {encC_bf, wd(i, 6), nullptr, nullptr, v2_bf, 1.f, 0};
            gemm_mfma<<<dim3(DD / 128, MM / 128, 5), 256, 0, stream>>>(J, MM, DD, DD);
        }
        flash_mfma<false, true, true><<<flashCrossG, 256, 0, stream>>>(
            q_bf, k1_bf, v1_bf, k2_bf, v2_bf, attnA, attnC, ml_buf);
        sum_bf16_kernel<<<NTD / 8 / 256, 256, 0, stream>>>(attnA, attnC, attnS, (int)NTD);
        avg_mfma_kernel<<<avgG, 64, 0, stream>>>(q_bf, k2_bf, ml_buf, avg_out, (i == 0) ? 1 : 0);
        {
            GemmJobs6 J{};
            J.j[0] = {attnS, wd(i, 7), x_buf, x_buf, nullptr, 1.f, 0};
            gemm_mfma<<<dim3(DD / 128, MM / 128, 1), 256, 0, stream>>>(J, MM, DD, DD);
        }

        // --- FFN ---
        ln_kernel<true><<<MM, 256, 0, stream>>>(x_buf, ln3_g0 + lOff, ln3_b0 + lOff, h_bf);
        {
            GemmJobs6 J{};
            J.j[0] = {h_bf, w1t + fOff, nullptr, nullptr, ffn_bf, 1.f, 1};
            gemm_mfma<<<dim3(FF / 128, MM / 128, 1), 256, 0, stream>>>(J, MM, FF, DD);
        }
        {
            GemmJobs6 J{};
            J.j[0] = {ffn_bf, w2t + fOff, x_buf, x_buf, nullptr, 1.f, 0};
            gemm_mfma<<<dim3(DD / 128, MM / 128, 1), 256, 0, stream>>>(J, MM, DD, FF);
        }
    }

    ln_kernel<false><<<MM, 256, 0, stream>>>(x_buf, out_g, out_b, x_out);
}

// Round 5
// 1149.554 us; speedup vs baseline: 13.1488x; 1.2118x over previous
//
#include <hip/hip_runtime.h>
#include <hip/hip_bf16.h>

// Problem dims (fixed by reference setup_inputs)
#define BB 2
#define TT 2048
#define DD 512
#define FF 2048
#define HH 8
#define DH 64
#define LL 2
#define MM (BB*TT)   // 4096 rows

typedef __attribute__((ext_vector_type(8))) short bf16x8;
typedef __attribute__((ext_vector_type(4))) float f32x4;

__device__ __forceinline__ float bf2f(unsigned short u) {
    return __uint_as_float(((unsigned int)u) << 16);
}
__device__ __forceinline__ unsigned short f2bf(float f) {
    unsigned int u = __float_as_uint(f);
    u += 0x7fffu + ((u >> 16) & 1u);   // round-to-nearest-even
    return (unsigned short)(u >> 16);
}
__device__ __forceinline__ void gload16(const void* g, void* l) {
    __builtin_amdgcn_global_load_lds((__attribute__((address_space(1))) void*)g,
                                     (__attribute__((address_space(3))) void*)l, 16, 0, 0);
}

// ---------------------------------------------------------------------------
// LayerNorm: one block (256 threads) per row of 512 floats. bf16 or f32 out.
// ---------------------------------------------------------------------------
template<bool BF16OUT>
__global__ __launch_bounds__(256) void ln_kernel(const float* __restrict__ x,
                                                 const float* __restrict__ g,
                                                 const float* __restrict__ b,
                                                 void* __restrict__ out)
{
    const int row = blockIdx.x;
    const int tid = threadIdx.x;
    const float2 v = ((const float2*)(x + (size_t)row * DD))[tid];
    float s = v.x + v.y;
    float q = v.x * v.x + v.y * v.y;
    #pragma unroll
    for (int off = 32; off; off >>= 1) {
        s += __shfl_down(s, off);
        q += __shfl_down(q, off);
    }
    __shared__ float ss[4], qq[4];
    const int wid = tid >> 6;
    if ((tid & 63) == 0) { ss[wid] = s; qq[wid] = q; }
    __syncthreads();
    s = ss[0] + ss[1] + ss[2] + ss[3];
    q = qq[0] + qq[1] + qq[2] + qq[3];
    const float mean = s * (1.0f / DD);
    const float var = q * (1.0f / DD) - mean * mean;
    const float inv = rsqrtf(var + 1e-6f);
    const float2 gg = ((const float2*)g)[tid];
    const float2 bb = ((const float2*)b)[tid];
    const float ox = gg.x * (v.x - mean) * inv + bb.x;
    const float oy = gg.y * (v.y - mean) * inv + bb.y;
    if (BF16OUT) {
        const unsigned int pk = (unsigned int)f2bf(ox) | ((unsigned int)f2bf(oy) << 16);
        ((unsigned int*)((unsigned short*)out + (size_t)row * DD))[tid] = pk;
    } else {
        float2 o; o.x = ox; o.y = oy;
        ((float2*)((float*)out + (size_t)row * DD))[tid] = o;
    }
}

// ---------------------------------------------------------------------------
// fp32 -> bf16 elementwise (enc inputs). n multiple of 2048.
// ---------------------------------------------------------------------------
__global__ __launch_bounds__(256) void cvt_kernel(const float* __restrict__ src,
                                                  unsigned short* __restrict__ dst, int n)
{
    const int i = (blockIdx.x * 256 + threadIdx.x) * 8;
    if (i >= n) return;
    const float4 a = *(const float4*)(src + i);
    const float4 b = *(const float4*)(src + i + 4);
    unsigned short o[8];
    o[0] = f2bf(a.x); o[1] = f2bf(a.y); o[2] = f2bf(a.z); o[3] = f2bf(a.w);
    o[4] = f2bf(b.x); o[5] = f2bf(b.y); o[6] = f2bf(b.z); o[7] = f2bf(b.w);
    *(bf16x8*)(dst + i) = *(bf16x8*)o;
}

// ---------------------------------------------------------------------------
// Weight convert + transpose: src fp32 [K][N] -> dst bf16 [N][K]. 32x32 tiles.
// ---------------------------------------------------------------------------
struct CvtJob { const float* s; unsigned short* d; };
struct CvtJobs16 { CvtJob j[16]; };

__global__ __launch_bounds__(256) void cvtT_kernel(CvtJobs16 P, int K, int N)
{
    __shared__ float t[32][33];
    const CvtJob jb = P.j[blockIdx.z];
    const int tx = threadIdx.x & 31, ty = threadIdx.x >> 5;
    const int gk = blockIdx.y << 5, gn = blockIdx.x << 5;
    #pragma unroll
    for (int i = 0; i < 4; ++i)
        t[ty + i * 8][tx] = jb.s[(size_t)(gk + ty + i * 8) * N + gn + tx];
    __syncthreads();
    #pragma unroll
    for (int i = 0; i < 4; ++i)
        jb.d[(size_t)(gn + ty + i * 8) * K + gk + tx] = f2bf(t[tx][ty + i * 8]);
}

// ---------------------------------------------------------------------------
// V transpose (bf16): v [b*T][512] head-slice -> vt [(b*8+h)*64 + d][T].
// ---------------------------------------------------------------------------
__global__ __launch_bounds__(256) void vtrans_kernel(const unsigned short* __restrict__ v,
                                                     unsigned short* __restrict__ vt)
{
    __shared__ unsigned short tile[64][72];
    const int b = blockIdx.z, h = blockIdx.y, t0 = blockIdx.x << 6;
    const int r = threadIdx.x >> 2;
    const int s4 = threadIdx.x & 3;
    const unsigned short* src = v + (size_t)(b * TT + t0 + r) * DD + h * DH + s4 * 16;
    *(bf16x8*)&tile[r][s4 * 16] = *(const bf16x8*)src;
    *(bf16x8*)&tile[r][s4 * 16 + 8] = *(const bf16x8*)(src + 8);
    __syncthreads();
    unsigned short o[16];
    #pragma unroll
    for (int e = 0; e < 16; ++e) o[e] = tile[s4 * 16 + e][r];
    unsigned short* dst = vt + ((size_t)(b * HH + h) * DH + r) * TT + t0 + s4 * 16;
    *(bf16x8*)dst = *(bf16x8*)o;
    *(bf16x8*)(dst + 8) = *(bf16x8*)(o + 8);
}

// ---------------------------------------------------------------------------
// bf16 MFMA GEMM: C[M,N] = scale * A[M,K] @ Wt[N,K]^T (+res fp32) (ReLU opt).
// 128x128 tile, BK=64, 256 threads = 4 waves (2x2 of 64x64).
// ---------------------------------------------------------------------------
struct GemmJob {
    const unsigned short* A;
    const unsigned short* Wt;
    const float* res;
    float* Cf;
    unsigned short* Cb;
    float scale;
    int relu;
};
struct GemmJobs6 { GemmJob j[6]; };

__global__ __launch_bounds__(256, 2) void gemm_mfma(GemmJobs6 P, int M, int N, int K)
{
    __shared__ __align__(16) unsigned char lds[32768];   // A: 0..16K, B: 16K..32K
    const GemmJob jb = P.j[blockIdx.z];
    const int tid = threadIdx.x, lane = tid & 63, w = tid >> 6;
    const int bn = blockIdx.x << 7, bm = blockIdx.y << 7;
    const int wr = (w >> 1) << 6, wc = (w & 1) << 6;
    const size_t strA = (size_t)K * 2;

    f32x4 acc[4][4] = {};
    const int akey = (lane & 7) << 4;
    const int frow = lane & 15;
    const int kq = (lane >> 4) << 4;

    for (int kt = 0; kt < K; kt += 64) {
        __syncthreads();
        #pragma unroll
        for (int c = 0; c < 4; ++c) {
            const int q = c * 4 + w;
            const int o = (q << 10) + (lane << 4);
            const int row = o >> 7;
            const int colb = (o & 127) ^ ((row & 7) << 4);
            gload16((const char*)jb.A + (size_t)(bm + row) * strA + kt * 2 + colb,
                    lds + (q << 10));
            gload16((const char*)jb.Wt + (size_t)(bn + row) * strA + kt * 2 + colb,
                    lds + 16384 + (q << 10));
        }
        asm volatile("s_waitcnt vmcnt(0)" ::: "memory");
        __syncthreads();
        #pragma unroll
        for (int kk = 0; kk < 2; ++kk) {
            bf16x8 av[4], bv[4];
            #pragma unroll
            for (int i = 0; i < 4; ++i) {
                const int rA = wr + (i << 4) + frow;
                av[i] = *(const bf16x8*)(lds + (rA << 7) + ((((kk << 6) + kq)) ^ akey));
                const int rB = wc + (i << 4) + frow;
                bv[i] = *(const bf16x8*)(lds + 16384 + (rB << 7) + ((((kk << 6) + kq)) ^ akey));
            }
            #pragma unroll
            for (int i = 0; i < 4; ++i)
                #pragma unroll
                for (int j = 0; j < 4; ++j)
                    acc[i][j] = __builtin_amdgcn_mfma_f32_16x16x32_bf16(av[i], bv[j], acc[i][j], 0, 0, 0);
        }
    }

    const int crow0 = (lane >> 4) << 2;
    const int ccol = lane & 15;
    #pragma unroll
    for (int i = 0; i < 4; ++i) {
        #pragma unroll
        for (int j = 0; j < 4; ++j) {
            #pragma unroll
            for (int r = 0; r < 4; ++r) {
                const int gm = bm + wr + (i << 4) + crow0 + r;
                const int gn = bn + wc + (j << 4) + ccol;
                float v = acc[i][j][r] * jb.scale;
                if (jb.relu) v = fmaxf(v, 0.f);
                const size_t idx = (size_t)gm * N + gn;
                if (jb.res) v += jb.res[idx];
                if (jb.Cf) jb.Cf[idx] = v;
                if (jb.Cb) jb.Cb[idx] = f2bf(v);
            }
        }
    }
}

// ---------------------------------------------------------------------------
// MFMA flash attention, independent-wave version (see header comment above).
// ---------------------------------------------------------------------------
template<bool CAUSAL, bool DUAL, bool STOREML>
__global__ __launch_bounds__(256, 4) void flash_mfma(
    const unsigned short* __restrict__ q,
    const unsigned short* __restrict__ ka, const unsigned short* __restrict__ vta,
    const unsigned short* __restrict__ kc, const unsigned short* __restrict__ vtc,
    unsigned short* __restrict__ outa, unsigned short* __restrict__ outc,
    float* __restrict__ ml)
{
    __shared__ __align__(16) char lds[8192];   // P: 2KB per wave
    const int tid = threadIdx.x;
    const int lane = tid & 63, w = tid >> 6;
    const int g4 = lane >> 4, c = lane & 15;

    const int f = blockIdx.x + 32 * (blockIdx.y + 8 * blockIdx.z);
    const int xcd = f & 7;
    const int tt = f >> 3;
    const int jq = tt & 31;
    const int grp = (tt >> 5) * 8 + xcd;
    int b, h, which;
    if (DUAL) { which = grp & 1; b = (grp >> 1) & 1; h = grp >> 2; }
    else      { which = 0;       b = grp & 1;        h = grp >> 1; }
    const int q0 = jq << 6;
    const int q0w = q0 + w * 16;

    const unsigned short* k  = (DUAL && which) ? kc : ka;
    const unsigned short* vt = (DUAL && which) ? vtc : vta;
    unsigned short* out = (DUAL && which) ? outc : outa;

    bf16x8 Qf[2];
    {
        const unsigned short* qp = q + (size_t)(b * TT + q0w + c) * DD + h * DH + (g4 << 3);
        Qf[0] = *(const bf16x8*)qp;
        Qf[1] = *(const bf16x8*)(qp + 32);
    }
    const unsigned short* kbase = k + (size_t)b * TT * DD + h * DH;
    const unsigned short* vtbase = vt + (size_t)(b * HH + h) * DH * TT;
    char* Pw = lds + w * 2048;
    const int pkey = (c & 7) << 4;

    f32x4 O[4] = {};
    float mval = -1e30f, lval = 0.f;

    const int nt = CAUSAL ? ((q0 >> 6) + 1) : (TT >> 6);
    for (int t = 0; t < nt; ++t) {
        const int kt = t << 6;
        bf16x8 av[4][2];
        #pragma unroll
        for (int i = 0; i < 4; ++i) {
            const unsigned short* kr = kbase + (size_t)(kt + (i << 4) + c) * DD + (g4 << 3);
            av[i][0] = *(const bf16x8*)kr;
            av[i][1] = *(const bf16x8*)(kr + 32);
        }
        f32x4 s[4] = {};
        #pragma unroll
        for (int kk = 0; kk < 2; ++kk)
            #pragma unroll
            for (int i = 0; i < 4; ++i)
                s[i] = __builtin_amdgcn_mfma_f32_16x16x32_bf16(av[i][kk], Qf[kk], s[i], 0, 0, 0);

        if (CAUSAL && t == nt - 1) {
            #pragma unroll
            for (int i = 0; i < 4; ++i)
                #pragma unroll
                for (int r = 0; r < 4; ++r)
                    if (((i << 4) + (g4 << 2) + r) > ((w << 4) + c)) s[i][r] = -1e30f;
        }

        float mx = -1e30f;
        #pragma unroll
        for (int i = 0; i < 4; ++i)
            #pragma unroll
            for (int r = 0; r < 4; ++r) mx = fmaxf(mx, s[i][r]);
        mx = fmaxf(mx, __shfl_xor(mx, 16));
        mx = fmaxf(mx, __shfl_xor(mx, 32));
        const float mn = fmaxf(mval, mx);
        const float scf = __expf(mval - mn);
        float ps = 0.f;
        #pragma unroll
        for (int i = 0; i < 4; ++i)
            #pragma unroll
            for (int r = 0; r < 4; ++r) {
                const float p = __expf(s[i][r] - mn);
                s[i][r] = p;
                ps += p;
            }
        ps += __shfl_xor(ps, 16);
        ps += __shfl_xor(ps, 32);
        lval = lval * scf + ps;
        mval = mn;

        #pragma unroll
        for (int i = 0; i < 4; ++i) {
            uint2 pk;
            pk.x = (unsigned int)f2bf(s[i][0]) | ((unsigned int)f2bf(s[i][1]) << 16);
            pk.y = (unsigned int)f2bf(s[i][2]) | ((unsigned int)f2bf(s[i][3]) << 16);
            const int baddr = (c << 7) + (((i << 4) + (g4 << 2)) << 1);
            *(uint2*)(Pw + (baddr ^ pkey)) = pk;
        }
        bf16x8 vb[4][2];
        #pragma unroll
        for (int jj = 0; jj < 4; ++jj) {
            const unsigned short* vr = vtbase + (size_t)((jj << 4) + c) * TT + kt + (g4 << 3);
            vb[jj][0] = *(const bf16x8*)vr;
            vb[jj][1] = *(const bf16x8*)(vr + 32);
        }
        #pragma unroll
        for (int r = 0; r < 4; ++r) {
            const float fr = __shfl(scf, (g4 << 2) + r);
            #pragma unroll
            for (int jj = 0; jj < 4; ++jj) O[jj][r] *= fr;
        }
        asm volatile("s_waitcnt lgkmcnt(0)" ::: "memory");
        __builtin_amdgcn_sched_barrier(0);
        #pragma unroll
        for (int kk = 0; kk < 2; ++kk) {
            const int off = ((c << 7) + (kk << 6) + (g4 << 4)) ^ pkey;
            const bf16x8 pa = *(const bf16x8*)(Pw + off);
            #pragma unroll
            for (int jj = 0; jj < 4; ++jj)
                O[jj] = __builtin_amdgcn_mfma_f32_16x16x32_bf16(pa, vb[jj][kk], O[jj], 0, 0, 0);
        }
    }

    float invL[4];
    #pragma unroll
    for (int r = 0; r < 4; ++r) invL[r] = 1.f / __shfl(lval, (g4 << 2) + r);
    #pragma unroll
    for (int jj = 0; jj < 4; ++jj)
        #pragma unroll
        for (int r = 0; r < 4; ++r) {
            const int qr = q0w + (g4 << 2) + r;
            out[(size_t)(b * TT + qr) * DD + h * DH + (jj << 4) + c] = f2bf(O[jj][r] * invL[r]);
        }
    if (STOREML && (!DUAL || which == 1) && lane < 16) {
        const size_t mi = (((size_t)b * HH + h) * TT + q0w + lane) * 2;
        ml[mi] = mval;
        ml[mi + 1] = lval;
    }
}

// ---------------------------------------------------------------------------
// bf16 elementwise add (attn_a + attn_c -> attn_sum).
// ---------------------------------------------------------------------------
__global__ __launch_bounds__(256) void sum_bf16_kernel(const unsigned short* __restrict__ a,
                                                       const unsigned short* __restrict__ b,
                                                       unsigned short* __restrict__ o, int n)
{
    const int i = (blockIdx.x * 256 + threadIdx.x) * 8;
    if (i >= n) return;
    const bf16x8 av = *(const bf16x8*)(a + i);
    const bf16x8 bv = *(const bf16x8*)(b + i);
    unsigned short ov[8];
    #pragma unroll
    for (int e = 0; e < 8; ++e)
        ov[e] = f2bf(bf2f(((const unsigned short*)&av)[e]) + bf2f(((const unsigned short*)&bv)[e]));
    *(bf16x8*)(o + i) = *(bf16x8*)ov;
}

// ---------------------------------------------------------------------------
// avg via MFMA: avg[b,q,kt] (+)= (1/(H*L)) * sum_h exp(q.kc - m)/l
// ---------------------------------------------------------------------------
__global__ __launch_bounds__(64) void avg_mfma_kernel(const unsigned short* __restrict__ qm,
                                                      const unsigned short* __restrict__ kcm,
                                                      const float* __restrict__ ml,
                                                      float* __restrict__ avg, int first)
{
    __shared__ __align__(16) unsigned char ldsQ[8192];
    __shared__ __align__(16) unsigned char ldsK[8192];
    __shared__ float sM[8][64];
    __shared__ float sIL[8][64];
    const int lane = threadIdx.x;
    const int kt0 = blockIdx.x << 6, q0 = blockIdx.y << 6, b = blockIdx.z;

    #pragma unroll
    for (int h = 0; h < 8; ++h) {
        const float* mp = ml + (((size_t)(b * HH + h) * TT) + q0 + lane) * 2;
        sM[h][lane] = mp[0];
        sIL[h][lane] = 1.f / mp[1];
    }

    float avac[4][4][4] = {};
    const int akey = (lane & 7) << 4;
    const int frow = lane & 15;
    const int kq = (lane >> 4) << 4;
    const int crow0 = (lane >> 4) << 2;

    for (int h = 0; h < 8; ++h) {
        __syncthreads();
        #pragma unroll
        for (int c = 0; c < 8; ++c) {
            const int o = (c << 10) + (lane << 4);
            const int row = o >> 7;
            const int colb = (o & 127) ^ ((row & 7) << 4);
            gload16((const char*)qm + ((size_t)(b * TT + q0 + row) * DD + h * DH) * 2 + colb,
                    ldsQ + (c << 10));
            gload16((const char*)kcm + ((size_t)(b * TT + kt0 + row) * DD + h * DH) * 2 + colb,
                    ldsK + (c << 10));
        }
        asm volatile("s_waitcnt vmcnt(0)" ::: "memory");
        __syncthreads();
        f32x4 s[4][4] = {};
        #pragma unroll
        for (int kk = 0; kk < 2; ++kk) {
            bf16x8 qv[4], kv[4];
            #pragma unroll
            for (int i = 0; i < 4; ++i) {
                qv[i] = *(const bf16x8*)(ldsQ + (((i << 4) + frow) << 7) + (((kk << 6) + kq) ^ akey));
                kv[i] = *(const bf16x8*)(ldsK + (((i << 4) + frow) << 7) + (((kk << 6) + kq) ^ akey));
            }
            #pragma unroll
            for (int i = 0; i < 4; ++i)
                #pragma unroll
                for (int j = 0; j < 4; ++j)
                    s[i][j] = __builtin_amdgcn_mfma_f32_16x16x32_bf16(qv[i], kv[j], s[i][j], 0, 0, 0);
        }
        #pragma unroll
        for (int i = 0; i < 4; ++i)
            #pragma unroll
            for (int j = 0; j < 4; ++j)
                #pragma unroll
                for (int r = 0; r < 4; ++r) {
                    const int qr = (i << 4) + crow0 + r;
                    avac[i][j][r] += __expf(s[i][j][r] - sM[h][qr]) * sIL[h][qr];
                }
    }

    float* dst = avg + ((size_t)b * TT + q0) * TT + kt0;
    #pragma unroll
    for (int i = 0; i < 4; ++i)
        #pragma unroll
        for (int j = 0; j < 4; ++j)
            #pragma unroll
            for (int r = 0; r < 4; ++r) {
                const int qr = (i << 4) + crow0 + r;
                const int kc = (j << 4) + (lane & 15);
                const float v = avac[i][j][r] * (1.f / (HH * LL));
                float* p = dst + (size_t)qr * TT + kc;
                *p = first ? v : (*p + v);
            }
}

// ---------------------------------------------------------------------------
extern "C" void kernel_launch(void* const* d_in, const int* in_sizes, int n_in,
                              void* d_out, int out_size, void* d_ws, size_t ws_size,
                              hipStream_t stream)
{
    const float* x_in   = (const float*)d_in[0];
    const float* enc_a  = (const float*)d_in[1];
    const float* enc_c  = (const float*)d_in[2];
    const float* sa_wq0 = (const float*)d_in[3];
    const float* sa_wk0 = (const float*)d_in[4];
    const float* sa_wv0 = (const float*)d_in[5];
    const float* sa_wo0 = (const float*)d_in[6];
    const float* ed_wq0 = (const float*)d_in[7];
    const float* ed_wk0 = (const float*)d_in[8];
    const float* ed_wv0 = (const float*)d_in[9];
    const float* ed_wo0 = (const float*)d_in[10];
    const float* ffn_w10 = (const float*)d_in[11];
    const float* ffn_w20 = (const float*)d_in[12];
    const float* ln1_g0 = (const float*)d_in[13];
    const float* ln1_b0 = (const float*)d_in[14];
    const float* ln2_g0 = (const float*)d_in[15];
    const float* ln2_b0 = (const float*)d_in[16];
    const float* ln3_g0 = (const float*)d_in[17];
    const float* ln3_b0 = (const float*)d_in[18];
    const float* out_g  = (const float*)d_in[19];
    const float* out_b  = (const float*)d_in[20];

    const size_t NTD = (size_t)MM * DD;       // 2,097,152
    const size_t MB = 1u << 20;
    char* W = (char*)d_ws;
    float*          x_buf   = (float*)(W);                   // 8 MB
    unsigned short* h_bf    = (unsigned short*)(W + 8 * MB); // 4 MB
    unsigned short* q_bf    = (unsigned short*)(W + 12 * MB);
    unsigned short* k1_bf   = (unsigned short*)(W + 16 * MB);
    unsigned short* v1_bf   = (unsigned short*)(W + 20 * MB);
    unsigned short* k2_bf   = (unsigned short*)(W + 24 * MB);
    unsigned short* v2_bf   = (unsigned short*)(W + 28 * MB);
    unsigned short* attnA   = (unsigned short*)(W + 32 * MB);
    unsigned short* attnC   = (unsigned short*)(W + 36 * MB);
    float*          ml_buf  = (float*)(W + 40 * MB);         // 256 KB
    unsigned short* encA_bf = (unsigned short*)(W + 41 * MB);
    unsigned short* encC_bf = (unsigned short*)(W + 45 * MB);
    unsigned short* wbf     = (unsigned short*)(W + 49 * MB); // 16.8 MB
    unsigned short* ffn_bf  = q_bf;   // alias (spans q..k2, all dead in FFN)
    unsigned short* attnS   = h_bf;   // alias (h/vt dead after flash)
    unsigned short* vt1     = h_bf;   // V^T in h region during flash
    unsigned short* vt2     = v1_bf;  // cross: V_c^T overwrites v1 (dead after vt1)

    unsigned short* w1t = wbf + (size_t)16 * DD * DD;
    unsigned short* w2t = w1t + (size_t)2 * DD * FF;
    auto wd = [&](int l, int which) { return wbf + ((size_t)(l * 8 + which)) * DD * DD; };

    float* x_out   = (float*)d_out;
    float* avg_out = (float*)d_out + NTD;

    hipMemcpyAsync(x_buf, x_in, NTD * sizeof(float), hipMemcpyDeviceToDevice, stream);

    {
        CvtJobs16 J{};
        const float* srcs[8] = {sa_wq0, sa_wk0, sa_wv0, sa_wo0, ed_wq0, ed_wk0, ed_wv0, ed_wo0};
        for (int l = 0; l < LL; ++l)
            for (int t = 0; t < 8; ++t) {
                J.j[l * 8 + t].s = srcs[t] + (size_t)l * DD * DD;
                J.j[l * 8 + t].d = wd(l, t);
            }
        cvtT_kernel<<<dim3(DD / 32, DD / 32, 16), 256, 0, stream>>>(J, DD, DD);
    }
    {
        CvtJobs16 J{};
        for (int l = 0; l < LL; ++l) { J.j[l].s = ffn_w10 + (size_t)l * DD * FF; J.j[l].d = w1t + (size_t)l * FF * DD; }
        cvtT_kernel<<<dim3(FF / 32, DD / 32, 2), 256, 0, stream>>>(J, DD, FF);
    }
    {
        CvtJobs16 J{};
        for (int l = 0; l < LL; ++l) { J.j[l].s = ffn_w20 + (size_t)l * FF * DD; J.j[l].d = w2t + (size_t)l * DD * FF; }
        cvtT_kernel<<<dim3(DD / 32, FF / 32, 2), 256, 0, stream>>>(J, FF, DD);
    }
    cvt_kernel<<<NTD / 8 / 256, 256, 0, stream>>>(enc_a, encA_bf, (int)NTD);
    cvt_kernel<<<NTD / 8 / 256, 256, 0, stream>>>(enc_c, encC_bf, (int)NTD);

    const dim3 vtG(TT / 64, HH, BB);
    const dim3 flashSelfG(TT / 64, HH, BB);      // (32, 8, 2)
    const dim3 flashCrossG(TT / 64, HH, BB * 2); // (32, 8, 4)
    const dim3 avgG(TT / 64, TT / 64, BB);
    const float qscale = 0.125f;

    for (int i = 0; i < LL; ++i) {
        const size_t fOff = (size_t)i * DD * FF;
        const size_t lOff = (size_t)i * DD;

        // --- self attention ---
        ln_kernel<true><<<MM, 256, 0, stream>>>(x_buf, ln1_g0 + lOff, ln1_b0 + lOff, h_bf);
        {
            GemmJobs6 J{};
            J.j[0] = {h_bf, wd(i, 0), nullptr, nullptr, q_bf, qscale, 0};
            J.j[1] = {h_bf, wd(i, 1), nullptr, nullptr, k1_bf, 1.f, 0};
            J.j[2] = {h_bf, wd(i, 2), nullptr, nullptr, v1_bf, 1.f, 0};
            gemm_mfma<<<dim3(DD / 128, MM / 128, 3), 256, 0, stream>>>(J, MM, DD, DD);
        }
        vtrans_kernel<<<vtG, 256, 0, stream>>>(v1_bf, vt1);
        flash_mfma<true, false, false><<<flashSelfG, 256, 0, stream>>>(
            q_bf, k1_bf, vt1, nullptr, nullptr, attnA, nullptr, nullptr);
        {
            GemmJobs6 J{};
            J.j[0] = {attnA, wd(i, 3), x_buf, x_buf, nullptr, 1.f, 0};
            gemm_mfma<<<dim3(DD / 128, MM / 128, 1), 256, 0, stream>>>(J, MM, DD, DD);
        }

        // --- cross attention (enc_a + enc_c, shared weights) ---
        ln_kernel<true><<<MM, 256, 0, stream>>>(x_buf, ln2_g0 + lOff, ln2_b0 + lOff, h_bf);
        {
            GemmJobs6 J{};
            J.j[0] = {h_bf,    wd(i, 4), nullptr, nullptr, q_bf, qscale, 0};
            J.j[1] = {encA_bf, wd(i, 5), nullptr, nullptr, k1_bf, 1.f, 0};
            J.j[2] = {encA_bf, wd(i, 6), nullptr, nullptr, v1_bf, 1.f, 0};
            J.j[3] = {encC_bf, wd(i, 5), nullptr, nullptr, k2_bf, 1.f, 0};
            J.j[4] = {encC_bf, wd(i, 6), nullptr, nullptr, v2_bf, 1.f, 0};
            gemm_mfma<<<dim3(DD / 128, MM / 128, 5), 256, 0, stream>>>(J, MM, DD, DD);
        }
        vtrans_kernel<<<vtG, 256, 0, stream>>>(v1_bf, vt1);   // V_a^T -> h region
        vtrans_kernel<<<vtG, 256, 0, stream>>>(v2_bf, vt2);   // V_c^T -> v1 region
        flash_mfma<false, true, true><<<flashCrossG, 256, 0, stream>>>(
            q_bf, k1_bf, vt1, k2_bf, vt2, attnA, attnC, ml_buf);
        sum_bf16_kernel<<<NTD / 8 / 256, 256, 0, stream>>>(attnA, attnC, attnS, (int)NTD);
        avg_mfma_kernel<<<avgG, 64, 0, stream>>>(q_bf, k2_bf, ml_buf, avg_out, (i == 0) ? 1 : 0);
        {
            GemmJobs6 J{};
            J.j[0] = {attnS, wd(i, 7), x_buf, x_buf, nullptr, 1.f, 0};
            gemm_mfma<<<dim3(DD / 128, MM / 128, 1), 256, 0, stream>>>(J, MM, DD, DD);
        }

        // --- FFN ---
        ln_kernel<true><<<MM, 256, 0, stream>>>(x_buf, ln3_g0 + lOff, ln3_b0 + lOff, h_bf);
        {
            GemmJobs6 J{};
            J.j[0] = {h_bf, w1t + fOff, nullptr, nullptr, ffn_bf, 1.f, 1};
            gemm_mfma<<<dim3(FF / 128, MM / 128, 1), 256, 0, stream>>>(J, MM, FF, DD);
        }
        {
            GemmJobs6 J{};
            J.j[0] = {ffn_bf, w2t + fOff, x_buf, x_buf, nullptr, 1.f, 0};
            gemm_mfma<<<dim3(DD / 128, MM / 128, 1), 256, 0, stream>>>(J, MM, DD, FF);
        }
    }

    ln_kernel<false><<<MM, 256, 0, stream>>>(x_buf, out_g, out_b, x_out);
}

// Round 6
// 653.771 us; speedup vs baseline: 23.1202x; 1.7583x over previous
//
#include <hip/hip_runtime.h>
#include <hip/hip_bf16.h>

// Problem dims (fixed by reference setup_inputs)
#define BB 2
#define TT 2048
#define DD 512
#define FF 2048
#define HH 8
#define DH 64
#define LL 2
#define MM (BB*TT)   // 4096 rows

typedef __attribute__((ext_vector_type(8))) short bf16x8;
typedef __attribute__((ext_vector_type(4))) float f32x4;

__device__ __forceinline__ float bf2f(unsigned short u) {
    return __uint_as_float(((unsigned int)u) << 16);
}
__device__ __forceinline__ unsigned short f2bf(float f) {
    unsigned int u = __float_as_uint(f);
    u += 0x7fffu + ((u >> 16) & 1u);   // round-to-nearest-even
    return (unsigned short)(u >> 16);
}
__device__ __forceinline__ void gload16(const void* g, void* l) {
    __builtin_amdgcn_global_load_lds((__attribute__((address_space(1))) void*)g,
                                     (__attribute__((address_space(3))) void*)l, 16, 0, 0);
}

// ---------------------------------------------------------------------------
// LayerNorm: one block (256 threads) per row of 512 floats. bf16 or f32 out.
// ---------------------------------------------------------------------------
template<bool BF16OUT>
__global__ __launch_bounds__(256) void ln_kernel(const float* __restrict__ x,
                                                 const float* __restrict__ g,
                                                 const float* __restrict__ b,
                                                 void* __restrict__ out)
{
    const int row = blockIdx.x;
    const int tid = threadIdx.x;
    const float2 v = ((const float2*)(x + (size_t)row * DD))[tid];
    float s = v.x + v.y;
    float q = v.x * v.x + v.y * v.y;
    #pragma unroll
    for (int off = 32; off; off >>= 1) {
        s += __shfl_down(s, off);
        q += __shfl_down(q, off);
    }
    __shared__ float ss[4], qq[4];
    const int wid = tid >> 6;
    if ((tid & 63) == 0) { ss[wid] = s; qq[wid] = q; }
    __syncthreads();
    s = ss[0] + ss[1] + ss[2] + ss[3];
    q = qq[0] + qq[1] + qq[2] + qq[3];
    const float mean = s * (1.0f / DD);
    const float var = q * (1.0f / DD) - mean * mean;
    const float inv = rsqrtf(var + 1e-6f);
    const float2 gg = ((const float2*)g)[tid];
    const float2 bb = ((const float2*)b)[tid];
    const float ox = gg.x * (v.x - mean) * inv + bb.x;
    const float oy = gg.y * (v.y - mean) * inv + bb.y;
    if (BF16OUT) {
        const unsigned int pk = (unsigned int)f2bf(ox) | ((unsigned int)f2bf(oy) << 16);
        ((unsigned int*)((unsigned short*)out + (size_t)row * DD))[tid] = pk;
    } else {
        float2 o; o.x = ox; o.y = oy;
        ((float2*)((float*)out + (size_t)row * DD))[tid] = o;
    }
}

// ---------------------------------------------------------------------------
// fp32 -> bf16 elementwise (enc inputs). n multiple of 2048.
// ---------------------------------------------------------------------------
__global__ __launch_bounds__(256) void cvt_kernel(const float* __restrict__ src,
                                                  unsigned short* __restrict__ dst, int n)
{
    const int i = (blockIdx.x * 256 + threadIdx.x) * 8;
    if (i >= n) return;
    const float4 a = *(const float4*)(src + i);
    const float4 b = *(const float4*)(src + i + 4);
    unsigned short o[8];
    o[0] = f2bf(a.x); o[1] = f2bf(a.y); o[2] = f2bf(a.z); o[3] = f2bf(a.w);
    o[4] = f2bf(b.x); o[5] = f2bf(b.y); o[6] = f2bf(b.z); o[7] = f2bf(b.w);
    *(bf16x8*)(dst + i) = *(bf16x8*)o;
}

// ---------------------------------------------------------------------------
// Weight convert + transpose: src fp32 [K][N] -> dst bf16 [N][K]. 32x32 tiles.
// ---------------------------------------------------------------------------
struct CvtJob { const float* s; unsigned short* d; };
struct CvtJobs16 { CvtJob j[16]; };

__global__ __launch_bounds__(256) void cvtT_kernel(CvtJobs16 P, int K, int N)
{
    __shared__ float t[32][33];
    const CvtJob jb = P.j[blockIdx.z];
    const int tx = threadIdx.x & 31, ty = threadIdx.x >> 5;
    const int gk = blockIdx.y << 5, gn = blockIdx.x << 5;
    #pragma unroll
    for (int i = 0; i < 4; ++i)
        t[ty + i * 8][tx] = jb.s[(size_t)(gk + ty + i * 8) * N + gn + tx];
    __syncthreads();
    #pragma unroll
    for (int i = 0; i < 4; ++i)
        jb.d[(size_t)(gn + ty + i * 8) * K + gk + tx] = f2bf(t[tx][ty + i * 8]);
}

// ---------------------------------------------------------------------------
// V transpose (bf16): v [b*T][512] head-slice -> vt [(b*8+h)*64 + d][T].
// ---------------------------------------------------------------------------
__global__ __launch_bounds__(256) void vtrans_kernel(const unsigned short* __restrict__ v,
                                                     unsigned short* __restrict__ vt)
{
    __shared__ unsigned short tile[64][72];
    const int b = blockIdx.z, h = blockIdx.y, t0 = blockIdx.x << 6;
    const int r = threadIdx.x >> 2;
    const int s4 = threadIdx.x & 3;
    const unsigned short* src = v + (size_t)(b * TT + t0 + r) * DD + h * DH + s4 * 16;
    *(bf16x8*)&tile[r][s4 * 16] = *(const bf16x8*)src;
    *(bf16x8*)&tile[r][s4 * 16 + 8] = *(const bf16x8*)(src + 8);
    __syncthreads();
    unsigned short o[16];
    #pragma unroll
    for (int e = 0; e < 16; ++e) o[e] = tile[s4 * 16 + e][r];
    unsigned short* dst = vt + ((size_t)(b * HH + h) * DH + r) * TT + t0 + s4 * 16;
    *(bf16x8*)dst = *(bf16x8*)o;
    *(bf16x8*)(dst + 8) = *(bf16x8*)(o + 8);
}

// ---------------------------------------------------------------------------
// bf16 MFMA GEMM: C[M,N] = scale * A[M,K] @ Wt[N,K]^T (+res fp32) (ReLU opt).
// 128x128 tile, BK=64, 256 threads = 4 waves (2x2 of 64x64).
// ---------------------------------------------------------------------------
struct GemmJob {
    const unsigned short* A;
    const unsigned short* Wt;
    const float* res;
    float* Cf;
    unsigned short* Cb;
    float scale;
    int relu;
};
struct GemmJobs6 { GemmJob j[6]; };

__global__ __launch_bounds__(256, 2) void gemm_mfma(GemmJobs6 P, int M, int N, int K)
{
    __shared__ __align__(16) unsigned char lds[32768];   // A: 0..16K, B: 16K..32K
    const GemmJob jb = P.j[blockIdx.z];
    const int tid = threadIdx.x, lane = tid & 63, w = tid >> 6;
    const int bn = blockIdx.x << 7, bm = blockIdx.y << 7;
    const int wr = (w >> 1) << 6, wc = (w & 1) << 6;
    const size_t strA = (size_t)K * 2;

    f32x4 acc[4][4] = {};
    const int akey = (lane & 7) << 4;
    const int frow = lane & 15;
    const int kq = (lane >> 4) << 4;

    for (int kt = 0; kt < K; kt += 64) {
        __syncthreads();
        #pragma unroll
        for (int c = 0; c < 4; ++c) {
            const int q = c * 4 + w;
            const int o = (q << 10) + (lane << 4);
            const int row = o >> 7;
            const int colb = (o & 127) ^ ((row & 7) << 4);
            gload16((const char*)jb.A + (size_t)(bm + row) * strA + kt * 2 + colb,
                    lds + (q << 10));
            gload16((const char*)jb.Wt + (size_t)(bn + row) * strA + kt * 2 + colb,
                    lds + 16384 + (q << 10));
        }
        asm volatile("s_waitcnt vmcnt(0)" ::: "memory");
        __syncthreads();
        #pragma unroll
        for (int kk = 0; kk < 2; ++kk) {
            bf16x8 av[4], bv[4];
            #pragma unroll
            for (int i = 0; i < 4; ++i) {
                const int rA = wr + (i << 4) + frow;
                av[i] = *(const bf16x8*)(lds + (rA << 7) + ((((kk << 6) + kq)) ^ akey));
                const int rB = wc + (i << 4) + frow;
                bv[i] = *(const bf16x8*)(lds + 16384 + (rB << 7) + ((((kk << 6) + kq)) ^ akey));
            }
            #pragma unroll
            for (int i = 0; i < 4; ++i)
                #pragma unroll
                for (int j = 0; j < 4; ++j)
                    acc[i][j] = __builtin_amdgcn_mfma_f32_16x16x32_bf16(av[i], bv[j], acc[i][j], 0, 0, 0);
        }
    }

    const int crow0 = (lane >> 4) << 2;
    const int ccol = lane & 15;
    #pragma unroll
    for (int i = 0; i < 4; ++i) {
        #pragma unroll
        for (int j = 0; j < 4; ++j) {
            #pragma unroll
            for (int r = 0; r < 4; ++r) {
                const int gm = bm + wr + (i << 4) + crow0 + r;
                const int gn = bn + wc + (j << 4) + ccol;
                float v = acc[i][j][r] * jb.scale;
                if (jb.relu) v = fmaxf(v, 0.f);
                const size_t idx = (size_t)gm * N + gn;
                if (jb.res) v += jb.res[idx];
                if (jb.Cf) jb.Cf[idx] = v;
                if (jb.Cb) jb.Cb[idx] = f2bf(v);
            }
        }
    }
}

// ---------------------------------------------------------------------------
// MFMA flash attention, v3: block-shared double-buffered LDS staging of K/V^T
// (global_load_lds, swizzled) + defer-max softmax (THR=8, no cross-lane ops
// in steady state; per-lane partial l combined once at the end).
// 4 waves/block; wave w owns q rows q0+w*16..+15; all waves walk all KV tiles.
// XCD swizzle: all 32 q-blocks of one (b,h,stream) group land on one XCD.
// ---------------------------------------------------------------------------
template<bool CAUSAL, bool DUAL, bool STOREML>
__global__ __launch_bounds__(256, 4) void flash_mfma(
    const unsigned short* __restrict__ q,
    const unsigned short* __restrict__ ka, const unsigned short* __restrict__ vta,
    const unsigned short* __restrict__ kc, const unsigned short* __restrict__ vtc,
    unsigned short* __restrict__ outa, unsigned short* __restrict__ outc,
    float* __restrict__ ml)
{
    // LDS: Kbuf[2] @ 0/8192, Vbuf[2] @ 16384/24576, P @ 32768 + w*2048
    __shared__ __align__(16) char lds[40960];
    const int tid = threadIdx.x;
    const int lane = tid & 63, w = tid >> 6;
    const int g4 = lane >> 4, c = lane & 15;

    const int f = blockIdx.x + 32 * (blockIdx.y + 8 * blockIdx.z);
    const int xcd = f & 7;
    const int tt = f >> 3;
    const int jq = tt & 31;
    const int grp = (tt >> 5) * 8 + xcd;
    int b, h, which;
    if (DUAL) { which = grp & 1; b = (grp >> 1) & 1; h = grp >> 2; }
    else      { which = 0;       b = grp & 1;        h = grp >> 1; }
    const int q0 = jq << 6;
    const int q0w = q0 + w * 16;

    const unsigned short* k  = (DUAL && which) ? kc : ka;
    const unsigned short* vt = (DUAL && which) ? vtc : vta;
    unsigned short* out = (DUAL && which) ? outc : outa;

    bf16x8 Qf[2];
    {
        const unsigned short* qp = q + (size_t)(b * TT + q0w + c) * DD + h * DH + (g4 << 3);
        Qf[0] = *(const bf16x8*)qp;
        Qf[1] = *(const bf16x8*)(qp + 32);
    }
    const char* kbase = (const char*)(k + (size_t)b * TT * DD + h * DH);
    const char* vtb   = (const char*)(vt + (size_t)(b * HH + h) * DH * TT);
    char* Pw = lds + 32768 + w * 2048;
    const int pkey = (c & 7) << 4;

    f32x4 O[4] = {};
    float mval = -1e30f, lpart = 0.f;

    const int nt = CAUSAL ? ((q0 >> 6) + 1) : (TT >> 6);

    // ---- stage tile t into buffer sel (4 gload16-pairs per wave) ----
    auto STAGE = [&](int t, int sel) {
        const int kt = t << 6;
        char* Kb = lds + sel * 8192;
        char* Vb = lds + 16384 + sel * 8192;
        #pragma unroll
        for (int c8 = 0; c8 < 2; ++c8) {
            const int qc = (c8 << 2) + w;            // chunk 0..7 (1KB each)
            const int o = (qc << 10) + (lane << 4);
            const int row = o >> 7;                  // 0..63
            const int colb = (o & 127) ^ ((row & 7) << 4);
            gload16(kbase + (size_t)(kt + row) * (DD * 2) + colb, Kb + (qc << 10));
            gload16(vtb + (size_t)row * (TT * 2) + kt * 2 + colb, Vb + (qc << 10));
        }
    };

    STAGE(0, 0);
    asm volatile("s_waitcnt vmcnt(0)" ::: "memory");
    __syncthreads();

    for (int t = 0; t < nt; ++t) {
        const int cur = t & 1;
        if (t + 1 < nt) STAGE(t + 1, cur ^ 1);
        const char* Kb = lds + cur * 8192;
        const char* Vb = lds + 16384 + cur * 8192;

        // ---- QK^T (swapped): s[i] = S^T[k=i*16+g4*4+r][q=c] ----
        f32x4 s[4] = {};
        #pragma unroll
        for (int kk = 0; kk < 2; ++kk) {
            bf16x8 av[4];
            #pragma unroll
            for (int i = 0; i < 4; ++i) {
                const int r = (i << 4) + c;
                av[i] = *(const bf16x8*)(Kb + (r << 7) + (((kk << 6) + (g4 << 4)) ^ ((r & 7) << 4)));
            }
            #pragma unroll
            for (int i = 0; i < 4; ++i)
                s[i] = __builtin_amdgcn_mfma_f32_16x16x32_bf16(av[i], Qf[kk], s[i], 0, 0, 0);
        }

        if (CAUSAL && t == nt - 1) {
            #pragma unroll
            for (int i = 0; i < 4; ++i)
                #pragma unroll
                for (int r = 0; r < 4; ++r)
                    if (((i << 4) + (g4 << 2) + r) > ((w << 4) + c)) s[i][r] = -1e30f;
        }

        // ---- defer-max online softmax (rare update path only) ----
        float pmax = -1e30f;
        #pragma unroll
        for (int i = 0; i < 4; ++i)
            #pragma unroll
            for (int r = 0; r < 4; ++r) pmax = fmaxf(pmax, s[i][r]);
        if (__any(pmax > mval + 8.f)) {
            float mx = fmaxf(pmax, __shfl_xor(pmax, 16));
            mx = fmaxf(mx, __shfl_xor(mx, 32));
            const float mn = fmaxf(mval, mx);
            const float scf = __expf(mval - mn);
            lpart *= scf;
            #pragma unroll
            for (int r = 0; r < 4; ++r) {
                const float fr = __shfl(scf, (g4 << 2) + r);
                #pragma unroll
                for (int jj = 0; jj < 4; ++jj) O[jj][r] *= fr;
            }
            mval = mn;
        }
        float ps = 0.f;
        #pragma unroll
        for (int i = 0; i < 4; ++i)
            #pragma unroll
            for (int r = 0; r < 4; ++r) {
                const float p = __expf(s[i][r] - mval);
                s[i][r] = p;
                ps += p;
            }
        lpart += ps;   // per-lane partial over this lane's k-slices

        // ---- P -> LDS (row q=c, swizzle key (c&7)<<4) ----
        #pragma unroll
        for (int i = 0; i < 4; ++i) {
            uint2 pk;
            pk.x = (unsigned int)f2bf(s[i][0]) | ((unsigned int)f2bf(s[i][1]) << 16);
            pk.y = (unsigned int)f2bf(s[i][2]) | ((unsigned int)f2bf(s[i][3]) << 16);
            const int baddr = (c << 7) + (((i << 4) + (g4 << 2)) << 1);
            *(uint2*)(Pw + (baddr ^ pkey)) = pk;
        }
        asm volatile("s_waitcnt lgkmcnt(0)" ::: "memory");
        __builtin_amdgcn_sched_barrier(0);

        // ---- PV: O += P @ Vt^T ----
        #pragma unroll
        for (int kk = 0; kk < 2; ++kk) {
            const bf16x8 pa = *(const bf16x8*)(Pw + (((c << 7) + (kk << 6) + (g4 << 4)) ^ pkey));
            bf16x8 vb[4];
            #pragma unroll
            for (int jj = 0; jj < 4; ++jj) {
                const int d = (jj << 4) + c;
                vb[jj] = *(const bf16x8*)(Vb + (d << 7) + (((kk << 6) + (g4 << 4)) ^ ((d & 7) << 4)));
            }
            #pragma unroll
            for (int jj = 0; jj < 4; ++jj)
                O[jj] = __builtin_amdgcn_mfma_f32_16x16x32_bf16(pa, vb[jj], O[jj], 0, 0, 0);
        }

        asm volatile("s_waitcnt vmcnt(0)" ::: "memory");
        __syncthreads();
    }

    // ---- epilogue: combine partial l across quarters, normalize, store ----
    float l2 = lpart + __shfl_xor(lpart, 16);
    const float ltot = l2 + __shfl_xor(l2, 32);
    float invL[4];
    #pragma unroll
    for (int r = 0; r < 4; ++r) invL[r] = 1.f / __shfl(ltot, (g4 << 2) + r);
    #pragma unroll
    for (int jj = 0; jj < 4; ++jj)
        #pragma unroll
        for (int r = 0; r < 4; ++r) {
            const int qr = q0w + (g4 << 2) + r;
            out[(size_t)(b * TT + qr) * DD + h * DH + (jj << 4) + c] = f2bf(O[jj][r] * invL[r]);
        }
    if (STOREML && (!DUAL || which == 1) && lane < 16) {
        const size_t mi = (((size_t)b * HH + h) * TT + q0w + lane) * 2;
        ml[mi] = mval;
        ml[mi + 1] = ltot;
    }
}

// ---------------------------------------------------------------------------
// bf16 elementwise add (attn_a + attn_c -> attn_sum).
// ---------------------------------------------------------------------------
__global__ __launch_bounds__(256) void sum_bf16_kernel(const unsigned short* __restrict__ a,
                                                       const unsigned short* __restrict__ b,
                                                       unsigned short* __restrict__ o, int n)
{
    const int i = (blockIdx.x * 256 + threadIdx.x) * 8;
    if (i >= n) return;
    const bf16x8 av = *(const bf16x8*)(a + i);
    const bf16x8 bv = *(const bf16x8*)(b + i);
    unsigned short ov[8];
    #pragma unroll
    for (int e = 0; e < 8; ++e)
        ov[e] = f2bf(bf2f(((const unsigned short*)&av)[e]) + bf2f(((const unsigned short*)&bv)[e]));
    *(bf16x8*)(o + i) = *(bf16x8*)ov;
}

// ---------------------------------------------------------------------------
// avg via MFMA: avg[b,q,kt] (+)= (1/(H*L)) * sum_h exp(q.kc - m)/l
// ---------------------------------------------------------------------------
__global__ __launch_bounds__(64) void avg_mfma_kernel(const unsigned short* __restrict__ qm,
                                                      const unsigned short* __restrict__ kcm,
                                                      const float* __restrict__ ml,
                                                      float* __restrict__ avg, int first)
{
    __shared__ __align__(16) unsigned char ldsQ[8192];
    __shared__ __align__(16) unsigned char ldsK[8192];
    __shared__ float sM[8][64];
    __shared__ float sIL[8][64];
    const int lane = threadIdx.x;
    const int kt0 = blockIdx.x << 6, q0 = blockIdx.y << 6, b = blockIdx.z;

    #pragma unroll
    for (int h = 0; h < 8; ++h) {
        const float* mp = ml + (((size_t)(b * HH + h) * TT) + q0 + lane) * 2;
        sM[h][lane] = mp[0];
        sIL[h][lane] = 1.f / mp[1];
    }

    float avac[4][4][4] = {};
    const int akey = (lane & 7) << 4;
    const int frow = lane & 15;
    const int kq = (lane >> 4) << 4;
    const int crow0 = (lane >> 4) << 2;

    for (int h = 0; h < 8; ++h) {
        __syncthreads();
        #pragma unroll
        for (int c = 0; c < 8; ++c) {
            const int o = (c << 10) + (lane << 4);
            const int row = o >> 7;
            const int colb = (o & 127) ^ ((row & 7) << 4);
            gload16((const char*)qm + ((size_t)(b * TT + q0 + row) * DD + h * DH) * 2 + colb,
                    ldsQ + (c << 10));
            gload16((const char*)kcm + ((size_t)(b * TT + kt0 + row) * DD + h * DH) * 2 + colb,
                    ldsK + (c << 10));
        }
        asm volatile("s_waitcnt vmcnt(0)" ::: "memory");
        __syncthreads();
        f32x4 s[4][4] = {};
        #pragma unroll
        for (int kk = 0; kk < 2; ++kk) {
            bf16x8 qv[4], kv[4];
            #pragma unroll
            for (int i = 0; i < 4; ++i) {
                qv[i] = *(const bf16x8*)(ldsQ + (((i << 4) + frow) << 7) + (((kk << 6) + kq) ^ akey));
                kv[i] = *(const bf16x8*)(ldsK + (((i << 4) + frow) << 7) + (((kk << 6) + kq) ^ akey));
            }
            #pragma unroll
            for (int i = 0; i < 4; ++i)
                #pragma unroll
                for (int j = 0; j < 4; ++j)
                    s[i][j] = __builtin_amdgcn_mfma_f32_16x16x32_bf16(qv[i], kv[j], s[i][j], 0, 0, 0);
        }
        #pragma unroll
        for (int i = 0; i < 4; ++i)
            #pragma unroll
            for (int j = 0; j < 4; ++j)
                #pragma unroll
                for (int r = 0; r < 4; ++r) {
                    const int qr = (i << 4) + crow0 + r;
                    avac[i][j][r] += __expf(s[i][j][r] - sM[h][qr]) * sIL[h][qr];
                }
    }

    float* dst = avg + ((size_t)b * TT + q0) * TT + kt0;
    #pragma unroll
    for (int i = 0; i < 4; ++i)
        #pragma unroll
        for (int j = 0; j < 4; ++j)
            #pragma unroll
            for (int r = 0; r < 4; ++r) {
                const int qr = (i << 4) + crow0 + r;
                const int kc = (j << 4) + (lane & 15);
                const float v = avac[i][j][r] * (1.f / (HH * LL));
                float* p = dst + (size_t)qr * TT + kc;
                *p = first ? v : (*p + v);
            }
}

// ---------------------------------------------------------------------------
extern "C" void kernel_launch(void* const* d_in, const int* in_sizes, int n_in,
                              void* d_out, int out_size, void* d_ws, size_t ws_size,
                              hipStream_t stream)
{
    const float* x_in   = (const float*)d_in[0];
    const float* enc_a  = (const float*)d_in[1];
    const float* enc_c  = (const float*)d_in[2];
    const float* sa_wq0 = (const float*)d_in[3];
    const float* sa_wk0 = (const float*)d_in[4];
    const float* sa_wv0 = (const float*)d_in[5];
    const float* sa_wo0 = (const float*)d_in[6];
    const float* ed_wq0 = (const float*)d_in[7];
    const float* ed_wk0 = (const float*)d_in[8];
    const float* ed_wv0 = (const float*)d_in[9];
    const float* ed_wo0 = (const float*)d_in[10];
    const float* ffn_w10 = (const float*)d_in[11];
    const float* ffn_w20 = (const float*)d_in[12];
    const float* ln1_g0 = (const float*)d_in[13];
    const float* ln1_b0 = (const float*)d_in[14];
    const float* ln2_g0 = (const float*)d_in[15];
    const float* ln2_b0 = (const float*)d_in[16];
    const float* ln3_g0 = (const float*)d_in[17];
    const float* ln3_b0 = (const float*)d_in[18];
    const float* out_g  = (const float*)d_in[19];
    const float* out_b  = (const float*)d_in[20];

    const size_t NTD = (size_t)MM * DD;       // 2,097,152
    const size_t MB = 1u << 20;
    char* W = (char*)d_ws;
    float*          x_buf   = (float*)(W);                   // 8 MB
    unsigned short* h_bf    = (unsigned short*)(W + 8 * MB); // 4 MB
    unsigned short* q_bf    = (unsigned short*)(W + 12 * MB);
    unsigned short* k1_bf   = (unsigned short*)(W + 16 * MB);
    unsigned short* v1_bf   = (unsigned short*)(W + 20 * MB);
    unsigned short* k2_bf   = (unsigned short*)(W + 24 * MB);
    unsigned short* v2_bf   = (unsigned short*)(W + 28 * MB);
    unsigned short* attnA   = (unsigned short*)(W + 32 * MB);
    unsigned short* attnC   = (unsigned short*)(W + 36 * MB);
    float*          ml_buf  = (float*)(W + 40 * MB);         // 256 KB
    unsigned short* encA_bf = (unsigned short*)(W + 41 * MB);
    unsigned short* encC_bf = (unsigned short*)(W + 45 * MB);
    unsigned short* wbf     = (unsigned short*)(W + 49 * MB); // 16.8 MB
    unsigned short* ffn_bf  = q_bf;   // alias (spans q..k2, all dead in FFN)
    unsigned short* attnS   = h_bf;   // alias (h/vt dead after flash)
    unsigned short* vt1     = h_bf;   // V^T in h region during flash
    unsigned short* vt2     = v1_bf;  // cross: V_c^T overwrites v1 (dead after vt1)

    unsigned short* w1t = wbf + (size_t)16 * DD * DD;
    unsigned short* w2t = w1t + (size_t)2 * DD * FF;
    auto wd = [&](int l, int which) { return wbf + ((size_t)(l * 8 + which)) * DD * DD; };

    float* x_out   = (float*)d_out;
    float* avg_out = (float*)d_out + NTD;

    hipMemcpyAsync(x_buf, x_in, NTD * sizeof(float), hipMemcpyDeviceToDevice, stream);

    {
        CvtJobs16 J{};
        const float* srcs[8] = {sa_wq0, sa_wk0, sa_wv0, sa_wo0, ed_wq0, ed_wk0, ed_wv0, ed_wo0};
        for (int l = 0; l < LL; ++l)
            for (int t = 0; t < 8; ++t) {
                J.j[l * 8 + t].s = srcs[t] + (size_t)l * DD * DD;
                J.j[l * 8 + t].d = wd(l, t);
            }
        cvtT_kernel<<<dim3(DD / 32, DD / 32, 16), 256, 0, stream>>>(J, DD, DD);
    }
    {
        CvtJobs16 J{};
        for (int l = 0; l < LL; ++l) { J.j[l].s = ffn_w10 + (size_t)l * DD * FF; J.j[l].d = w1t + (size_t)l * FF * DD; }
        cvtT_kernel<<<dim3(FF / 32, DD / 32, 2), 256, 0, stream>>>(J, DD, FF);
    }
    {
        CvtJobs16 J{};
        for (int l = 0; l < LL; ++l) { J.j[l].s = ffn_w20 + (size_t)l * FF * DD; J.j[l].d = w2t + (size_t)l * DD * FF; }
        cvtT_kernel<<<dim3(DD / 32, FF / 32, 2), 256, 0, stream>>>(J, FF, DD);
    }
    cvt_kernel<<<NTD / 8 / 256, 256, 0, stream>>>(enc_a, encA_bf, (int)NTD);
    cvt_kernel<<<NTD / 8 / 256, 256, 0, stream>>>(enc_c, encC_bf, (int)NTD);

    const dim3 vtG(TT / 64, HH, BB);
    const dim3 flashSelfG(TT / 64, HH, BB);      // (32, 8, 2)
    const dim3 flashCrossG(TT / 64, HH, BB * 2); // (32, 8, 4)
    const dim3 avgG(TT / 64, TT / 64, BB);
    const float qscale = 0.125f;

    for (int i = 0; i < LL; ++i) {
        const size_t fOff = (size_t)i * DD * FF;
        const size_t lOff = (size_t)i * DD;

        // --- self attention ---
        ln_kernel<true><<<MM, 256, 0, stream>>>(x_buf, ln1_g0 + lOff, ln1_b0 + lOff, h_bf);
        {
            GemmJobs6 J{};
            J.j[0] = {h_bf, wd(i, 0), nullptr, nullptr, q_bf, qscale, 0};
            J.j[1] = {h_bf, wd(i, 1), nullptr, nullptr, k1_bf, 1.f, 0};
            J.j[2] = {h_bf, wd(i, 2), nullptr, nullptr, v1_bf, 1.f, 0};
            gemm_mfma<<<dim3(DD / 128, MM / 128, 3), 256, 0, stream>>>(J, MM, DD, DD);
        }
        vtrans_kernel<<<vtG, 256, 0, stream>>>(v1_bf, vt1);
        flash_mfma<true, false, false><<<flashSelfG, 256, 0, stream>>>(
            q_bf, k1_bf, vt1, nullptr, nullptr, attnA, nullptr, nullptr);
        {
            GemmJobs6 J{};
            J.j[0] = {attnA, wd(i, 3), x_buf, x_buf, nullptr, 1.f, 0};
            gemm_mfma<<<dim3(DD / 128, MM / 128, 1), 256, 0, stream>>>(J, MM, DD, DD);
        }

        // --- cross attention (enc_a + enc_c, shared weights) ---
        ln_kernel<true><<<MM, 256, 0, stream>>>(x_buf, ln2_g0 + lOff, ln2_b0 + lOff, h_bf);
        {
            GemmJobs6 J{};
            J.j[0] = {h_bf,    wd(i, 4), nullptr, nullptr, q_bf, qscale, 0};
            J.j[1] = {encA_bf, wd(i, 5), nullptr, nullptr, k1_bf, 1.f, 0};
            J.j[2] = {encA_bf, wd(i, 6), nullptr, nullptr, v1_bf, 1.f, 0};
            J.j[3] = {encC_bf, wd(i, 5), nullptr, nullptr, k2_bf, 1.f, 0};
            J.j[4] = {encC_bf, wd(i, 6), nullptr, nullptr, v2_bf, 1.f, 0};
            gemm_mfma<<<dim3(DD / 128, MM / 128, 5), 256, 0, stream>>>(J, MM, DD, DD);
        }
        vtrans_kernel<<<vtG, 256, 0, stream>>>(v1_bf, vt1);   // V_a^T -> h region
        vtrans_kernel<<<vtG, 256, 0, stream>>>(v2_bf, vt2);   // V_c^T -> v1 region
        flash_mfma<false, true, true><<<flashCrossG, 256, 0, stream>>>(
            q_bf, k1_bf, vt1, k2_bf, vt2, attnA, attnC, ml_buf);
        sum_bf16_kernel<<<NTD / 8 / 256, 256, 0, stream>>>(attnA, attnC, attnS, (int)NTD);
        avg_mfma_kernel<<<avgG, 64, 0, stream>>>(q_bf, k2_bf, ml_buf, avg_out, (i == 0) ? 1 : 0);
        {
            GemmJobs6 J{};
            J.j[0] = {attnS, wd(i, 7), x_buf, x_buf, nullptr, 1.f, 0};
            gemm_mfma<<<dim3(DD / 128, MM / 128, 1), 256, 0, stream>>>(J, MM, DD, DD);
        }

        // --- FFN ---
        ln_kernel<true><<<MM, 256, 0, stream>>>(x_buf, ln3_g0 + lOff, ln3_b0 + lOff, h_bf);
        {
            GemmJobs6 J{};
            J.j[0] = {h_bf, w1t + fOff, nullptr, nullptr, ffn_bf, 1.f, 1};
            gemm_mfma<<<dim3(FF / 128, MM / 128, 1), 256, 0, stream>>>(J, MM, FF, DD);
        }
        {
            GemmJobs6 J{};
            J.j[0] = {ffn_bf, w2t + fOff, x_buf, x_buf, nullptr, 1.f, 0};
            gemm_mfma<<<dim3(DD / 128, MM / 128, 1), 256, 0, stream>>>(J, MM, DD, FF);
        }
    }

    ln_kernel<false><<<MM, 256, 0, stream>>>(x_buf, out_g, out_b, x_out);
}